// Round 12
// baseline (447.321 us; speedup 1.0000x reference)
//
#include <hip/hip_runtime.h>
#include <hip/hip_bf16.h>

typedef __attribute__((ext_vector_type(8))) short bf16x8;
typedef __attribute__((ext_vector_type(4))) float f32x4;
typedef __attribute__((ext_vector_type(16))) float f32x16;
typedef unsigned short u16;
typedef unsigned int u32;

#define RMS_EPS 1.1920929e-07f

constexpr int Bb = 2, Ss = 2048, DM = 2048, NH = 16;
constexpr int MROWS = Bb * Ss; // 4096

__device__ __forceinline__ u16 f2bf(float f) {
    __hip_bfloat16 h = __float2bfloat16(f);
    return *reinterpret_cast<u16*>(&h);
}

__device__ __forceinline__ float exp2_fast(float x) {
    float r; asm("v_exp_f32 %0, %1" : "=v"(r) : "v"(x)); return r;
}

__device__ __forceinline__ void gload16(const void* g, void* l) {
    __builtin_amdgcn_global_load_lds(
        (const __attribute__((address_space(1))) unsigned int*)g,
        (__attribute__((address_space(3))) unsigned int*)l, 16, 0, 0);
}

// ---------------- merged fp32 -> bf16 convert (7 segments, sizes fixed) -------
__global__ __launch_bounds__(256) void cvt_all(
    const float* __restrict__ s0, u16* __restrict__ d0,
    const float* __restrict__ s1, u16* __restrict__ d1,
    const float* __restrict__ s2, u16* __restrict__ d2,
    const float* __restrict__ s3, u16* __restrict__ d3,
    const float* __restrict__ s4, u16* __restrict__ d4,
    const float* __restrict__ s5, u16* __restrict__ d5,
    const float* __restrict__ s6, u16* __restrict__ d6)
{
    int i = blockIdx.x * 256 + threadIdx.x;   // float4 index; grid covers exactly 5373952
    const float* s; u16* d; int off;
    if (i < 2097152)      { s = s0; d = d0; off = 0; }
    else if (i < 2621440) { s = s1; d = d1; off = 2097152; }
    else if (i < 2883584) { s = s2; d = d2; off = 2621440; }
    else if (i < 3407872) { s = s3; d = d3; off = 2883584; }
    else if (i < 3932160) { s = s4; d = d4; off = 3407872; }
    else if (i < 4325376) { s = s5; d = d5; off = 3932160; }
    else                  { s = s6; d = d6; off = 4325376; }
    int j = i - off;
    float4 v = reinterpret_cast<const float4*>(s)[j];
    ushort4 o;
    o.x = f2bf(v.x); o.y = f2bf(v.y); o.z = f2bf(v.z); o.w = f2bf(v.w);
    reinterpret_cast<ushort4*>(d)[j] = o;
}

__global__ void build_bcat(const float* __restrict__ qb, const float* __restrict__ kvb,
                           const float* __restrict__ krb, float* __restrict__ bcat) {
    int i = blockIdx.x * 256 + threadIdx.x;
    if (i < 1024) bcat[i] = qb[i];
    else if (i < 1536) bcat[i] = kvb[i - 1024];
    else if (i < 2560) bcat[i] = krb[i - 1536];
}

// XCD-chunked bijective block remap (T1). Requires nwg % 8 == 0.
__device__ __forceinline__ void xcd_remap(int& bx, int& by) {
    int nx = gridDim.x, ny = gridDim.y;
    int nwg = nx * ny;
    if ((nwg & 7) != 0) return;
    int flat = blockIdx.x + nx * blockIdx.y;
    int chunk = nwg >> 3;
    int wg = (flat & 7) * chunk + (flat >> 3);
    by = wg % ny;          // M-tile fastest within an XCD chunk
    bx = wg / ny;          // few N-columns per XCD -> B-panel L2 reuse
}

// ---------------- GEMM: C(M,N) = A(M,K) * Bt(N,K)^T + bias ----------------
// 2-phase double-buffered: STAGE(t+1) issued BEFORE compute(t); 1 barrier/K-step.
template <typename OutT>
__global__ __launch_bounds__(256) void gemm_bt(
    const u16* __restrict__ A, const u16* __restrict__ Bt,
    const float* __restrict__ bias, OutT* __restrict__ C,
    int M, int N, int K)
{
    __shared__ alignas(16) u16 sA[2][128 * 32];
    __shared__ alignas(16) u16 sB[2][128 * 32];
    const int tid = threadIdx.x;
    const int lane = tid & 63;
    const int w = tid >> 6;
    const int wr = w >> 1, wc = w & 1;
    const int l16 = lane & 15, lq = lane >> 4;
    int bx = blockIdx.x, by = blockIdx.y;
    xcd_remap(bx, by);
    const int tileM = by * 128;
    const int tileN = bx * 128;

    f32x4 acc[4][4];
#pragma unroll
    for (int m = 0; m < 4; m++)
#pragma unroll
        for (int n = 0; n < 4; n++)
#pragma unroll
            for (int r = 0; r < 4; r++) acc[m][n][r] = 0.f;

    const int srow = w * 16 + (lane >> 2);
    const int scol = (lane & 3) * 8;
    const u16* gA0 = A + (size_t)(tileM + srow) * K + scol;
    const u16* gA1 = A + (size_t)(tileM + srow + 64) * K + scol;
    const u16* gB0 = Bt + (size_t)(tileN + srow) * K + scol;
    const u16* gB1 = Bt + (size_t)(tileN + srow + 64) * K + scol;
    u16* lA0 = &sA[0][0] + w * 512;
    u16* lA1 = &sA[0][0] + 2048 + w * 512;
    u16* lB0 = &sB[0][0] + w * 512;
    u16* lB1 = &sB[0][0] + 2048 + w * 512;

    int aoff[4], boff[4];
#pragma unroll
    for (int m = 0; m < 4; m++) aoff[m] = (wr * 64 + m * 16 + l16) * 32 + lq * 8;
#pragma unroll
    for (int n = 0; n < 4; n++) boff[n] = (wc * 64 + n * 16 + l16) * 32 + lq * 8;

    const int nk = K >> 5;
    // prologue: stage tile 0 into buffer 0
    gload16(gA0, lA0);
    gload16(gA1, lA1);
    gload16(gB0, lB0);
    gload16(gB1, lB1);
    __syncthreads();
    int cur = 0;
    for (int kk = 0; kk < nk; ++kk) {
        if (kk + 1 < nk) {   // issue next-tile DMA into other buffer (overlaps compute)
            int nb = (cur ^ 1) * 4096;
            const u16* a0 = gA0 + (size_t)(kk + 1) * 32;
            const u16* a1 = gA1 + (size_t)(kk + 1) * 32;
            const u16* b0 = gB0 + (size_t)(kk + 1) * 32;
            const u16* b1 = gB1 + (size_t)(kk + 1) * 32;
            gload16(a0, lA0 + nb);
            gload16(a1, lA1 + nb);
            gload16(b0, lB0 + nb);
            gload16(b1, lB1 + nb);
        }
        const u16* bA = &sA[0][0] + cur * 4096;
        const u16* bB = &sB[0][0] + cur * 4096;
        bf16x8 af[4], bfr[4];
#pragma unroll
        for (int m = 0; m < 4; m++) af[m] = *(const bf16x8*)&bA[aoff[m]];
#pragma unroll
        for (int n = 0; n < 4; n++) bfr[n] = *(const bf16x8*)&bB[boff[n]];
        __builtin_amdgcn_s_setprio(1);
#pragma unroll
        for (int m = 0; m < 4; m++)
#pragma unroll
            for (int n = 0; n < 4; n++)
                acc[m][n] = __builtin_amdgcn_mfma_f32_16x16x32_bf16(af[m], bfr[n], acc[m][n], 0, 0, 0);
        __builtin_amdgcn_s_setprio(0);
        __syncthreads();   // drains staged DMA (had full compute phase to land) + read-done
        cur ^= 1;
    }

#pragma unroll
    for (int n = 0; n < 4; n++) {
        int col = tileN + wc * 64 + n * 16 + l16;
        float bv = bias ? bias[col] : 0.f;
#pragma unroll
        for (int m = 0; m < 4; m++) {
            int rowb = tileM + wr * 64 + m * 16 + (lq << 2);
#pragma unroll
            for (int r = 0; r < 4; r++) {
                float v = acc[m][n][r] + bv;
                if constexpr (sizeof(OutT) == 2)
                    C[(size_t)(rowb + r) * N + col] = (OutT)f2bf(v);
                else
                    C[(size_t)(rowb + r) * N + col] = (OutT)v;
            }
        }
    }
}

// ---------------- fused down-proj GEMM: N=2560 (1024 q | 512 kv | 1024 rope) ----
// Same 2-phase schedule as gemm_bt.
__global__ __launch_bounds__(256) void gemm_down(
    const u16* __restrict__ A, const u16* __restrict__ Bt,
    const float* __restrict__ bcat, float* __restrict__ dcat,
    u16* __restrict__ krbuf)
{
    constexpr int K = 2048;
    __shared__ alignas(16) u16 sA[2][128 * 32];
    __shared__ alignas(16) u16 sB[2][128 * 32];
    const int tid = threadIdx.x;
    const int lane = tid & 63;
    const int w = tid >> 6;
    const int wr = w >> 1, wc = w & 1;
    const int l16 = lane & 15, lq = lane >> 4;
    int bx = blockIdx.x, by = blockIdx.y;
    xcd_remap(bx, by);
    const int tileM = by * 128;
    const int tileN = bx * 128;

    f32x4 acc[4][4];
#pragma unroll
    for (int m = 0; m < 4; m++)
#pragma unroll
        for (int n = 0; n < 4; n++)
#pragma unroll
            for (int r = 0; r < 4; r++) acc[m][n][r] = 0.f;

    const int srow = w * 16 + (lane >> 2);
    const int scol = (lane & 3) * 8;
    const u16* gA0 = A + (size_t)(tileM + srow) * K + scol;
    const u16* gA1 = A + (size_t)(tileM + srow + 64) * K + scol;
    const u16* gB0 = Bt + (size_t)(tileN + srow) * K + scol;
    const u16* gB1 = Bt + (size_t)(tileN + srow + 64) * K + scol;
    u16* lA0 = &sA[0][0] + w * 512;
    u16* lA1 = &sA[0][0] + 2048 + w * 512;
    u16* lB0 = &sB[0][0] + w * 512;
    u16* lB1 = &sB[0][0] + 2048 + w * 512;

    int aoff[4], boff[4];
#pragma unroll
    for (int m = 0; m < 4; m++) aoff[m] = (wr * 64 + m * 16 + l16) * 32 + lq * 8;
#pragma unroll
    for (int n = 0; n < 4; n++) boff[n] = (wc * 64 + n * 16 + l16) * 32 + lq * 8;

    const int nk = K >> 5;
    gload16(gA0, lA0);
    gload16(gA1, lA1);
    gload16(gB0, lB0);
    gload16(gB1, lB1);
    __syncthreads();
    int cur = 0;
    for (int kk = 0; kk < nk; ++kk) {
        if (kk + 1 < nk) {
            int nb = (cur ^ 1) * 4096;
            const u16* a0 = gA0 + (size_t)(kk + 1) * 32;
            const u16* a1 = gA1 + (size_t)(kk + 1) * 32;
            const u16* b0 = gB0 + (size_t)(kk + 1) * 32;
            const u16* b1 = gB1 + (size_t)(kk + 1) * 32;
            gload16(a0, lA0 + nb);
            gload16(a1, lA1 + nb);
            gload16(b0, lB0 + nb);
            gload16(b1, lB1 + nb);
        }
        const u16* bA = &sA[0][0] + cur * 4096;
        const u16* bB = &sB[0][0] + cur * 4096;
        bf16x8 af[4], bfr[4];
#pragma unroll
        for (int m = 0; m < 4; m++) af[m] = *(const bf16x8*)&bA[aoff[m]];
#pragma unroll
        for (int n = 0; n < 4; n++) bfr[n] = *(const bf16x8*)&bB[boff[n]];
        __builtin_amdgcn_s_setprio(1);
#pragma unroll
        for (int m = 0; m < 4; m++)
#pragma unroll
            for (int n = 0; n < 4; n++)
                acc[m][n] = __builtin_amdgcn_mfma_f32_16x16x32_bf16(af[m], bfr[n], acc[m][n], 0, 0, 0);
        __builtin_amdgcn_s_setprio(0);
        __syncthreads();
        cur ^= 1;
    }

    const bool isrope = (tileN >= 1536);
#pragma unroll
    for (int n = 0; n < 4; n++) {
        int col = tileN + wc * 64 + n * 16 + l16;
        float bv = bcat[col];
#pragma unroll
        for (int m = 0; m < 4; m++) {
            int rowb = tileM + wr * 64 + m * 16 + (lq << 2);
#pragma unroll
            for (int r = 0; r < 4; r++) {
                float v = acc[m][n][r] + bv;
                if (!isrope) dcat[(size_t)(rowb + r) * 1536 + col] = v;
                else         krbuf[(size_t)(rowb + r) * 1024 + (col - 1536)] = f2bf(v);
            }
        }
    }
}

// ---------------- RMS norm (row-wise, strided in), fp32 in -> bf16 out --------
template <int C>
__global__ __launch_bounds__(256) void rmsnorm_bf16(
    const float* __restrict__ in, int istride, const float* __restrict__ wgt, u16* __restrict__ out)
{
    const int row = blockIdx.x;
    const int tid = threadIdx.x;
    constexpr int PER = C / 256;
    const float* p = in + (size_t)row * istride;
    float v[PER];
    float ss = 0.f;
#pragma unroll
    for (int i = 0; i < PER; i++) { v[i] = p[tid + i * 256]; ss += v[i] * v[i]; }
#pragma unroll
    for (int o = 32; o; o >>= 1) ss += __shfl_xor(ss, o, 64);
    __shared__ float red[4];
    if ((tid & 63) == 0) red[tid >> 6] = ss;
    __syncthreads();
    float tot = red[0] + red[1] + red[2] + red[3];
    float inv = rsqrtf(tot / (float)C + RMS_EPS);
    u16* q = out + (size_t)row * C;
#pragma unroll
    for (int i = 0; i < PER; i++) {
        int c = tid + i * 256;
        q[c] = f2bf(v[i] * inv * wgt[c]);
    }
}

// ---------------- V transpose: kvbuf[token][h*192+64+d] -> vT[(h*128+d)*4096+token]
__global__ __launch_bounds__(256) void transpose_v(
    const u16* __restrict__ kvbuf, u16* __restrict__ vT)
{
    __shared__ alignas(16) u16 tile[64][72];
    const int tid = threadIdx.x;
    const int t0 = blockIdx.x * 64;
    const int h = blockIdx.y >> 1, dh = blockIdx.y & 1;
    const int trow = tid >> 2, c8 = (tid & 3) * 8;
    const u16* src = kvbuf + (size_t)(t0 + trow) * 3072 + h * 192 + 64 + dh * 64 + c8;
    *(bf16x8*)&tile[trow][c8]      = *(const bf16x8*)src;
    *(bf16x8*)&tile[trow][c8 + 32] = *(const bf16x8*)(src + 32);
    __syncthreads();
    const int drow = tid >> 2, tc8 = (tid & 3) * 8;
    bf16x8 a, b2;
#pragma unroll
    for (int j = 0; j < 8; j++) {
        a[j]  = (short)tile[tc8 + j][drow];
        b2[j] = (short)tile[tc8 + 32 + j][drow];
    }
    u16* dst = vT + (size_t)(h * 128 + dh * 64 + drow) * MROWS + t0 + tc8;
    *(bf16x8*)dst = a;
    *(bf16x8*)(dst + 32) = b2;
}

// ---------------- causal flash attention: in-block K-split, 8 waves ----------
// Block = (bh, qt), 512 threads. Waves 0-3 (group A) process k-tiles [0, qt+1);
// waves 4-7 (group B) process [qt+1, 2qt+2). Both groups run EXACTLY qt+1
// iterations (2qt+2 even) -> aligned barriers. Each group has private K/V LDS.
// End: B passes (m,l,O) via LDS (padded [32][132] f32/wave, overlays staging);
// A rescale-merges and writes. Masked-dead B-lanes self-heal (defer-max rescale
// x0 at first valid tile; fully-dead lanes get merge weight 0).
// LDS ~68.6 KB, VGPR<=128 via launch_bounds(512,4) -> 2 blocks/CU = 16 waves/CU.
__global__ __launch_bounds__(512, 4) void mla_attn(
    const u16* __restrict__ qbuf,   // (4096, 2048) head-major h*128
    const u16* __restrict__ kvbuf,  // (4096, 3072) per head 192: knope(64) v(128)
    const u16* __restrict__ krbuf,  // (4096, 1024) per head 64
    const u16* __restrict__ vT,     // (h*128+d, 4096 tokens)
    u16* __restrict__ obuf)         // (4096, 2048)
{
    const int bh = blockIdx.x;
    const int y = blockIdx.y;
    const int ii = y & 7, jj = y >> 3;
    const int qt = jj ? (15 - 2 * ii) : (2 * ii);
    const int b = bh >> 4, hh = bh & 15;
    const int tid = threadIdx.x, lane = tid & 63;
    const int w8 = tid >> 6;
    const int grp = w8 >> 2;        // 0 = A (low k half), 1 = B (high k half)
    const int w = w8 & 3;           // wave-in-group; q rows w*32..w*32+31
    const int l31 = lane & 31, hx = lane >> 5;
    const int tg = tid & 255;       // thread-in-group

    __shared__ alignas(16) char smem[68608];
    char* sK  = smem + grp * 16384;            // [64][128] bf16, XOR-swizzled
    char* sVt = smem + 32768 + grp * 16384;    // [128][64] bf16, XOR-swizzled
    float* mO  = (float*)smem;                 // merge: [4 waves][32 q][132] f32
    float* mml = (float*)(smem + 67584);       // merge: [4 waves][32 q][2] f32

    const int rowbase = b * Ss;
    const int q0 = qt * 128;
    const int niter = qt + 1;
    const int kbase = grp ? niter : 0;

    const int sr = tg >> 2, sc = (tg & 3) * 32;   // K staging (group-local)
    const int vd = tg >> 1, vh = (tg & 1) * 32;   // V staging (group-local)
    const float C1 = 0.12751742f;    // softmax_scale * log2(e)
    const float THRR = 90.5f;        // defer-max threshold (raw score units)

    // Q fragments: lane (q=l31, hx) needs d-chunks (2c + hx), c = 0..7
    bf16x8 qf[8];
    {
        const u16* qp = qbuf + (size_t)(rowbase + q0 + w * 32 + l31) * 2048 + hh * 128;
#pragma unroll
        for (int c = 0; c < 8; c++) qf[c] = *(const bf16x8*)(qp + (2 * c + hx) * 8);
    }
    float mi = -3e38f, li = 0.f;
    f32x16 o[4];
#pragma unroll
    for (int d = 0; d < 4; d++)
#pragma unroll
        for (int i = 0; i < 16; i++) o[d][i] = 0.f;

    bf16x8 kr[4], vr[4];
    {   // prologue: tile kbase -> regs
        const int krow = rowbase + kbase * 64 + sr;
        const u16* src = (sc < 64)
            ? kvbuf + (size_t)krow * 3072 + hh * 192 + sc
            : krbuf + (size_t)krow * 1024 + hh * 64 + (sc - 64);
#pragma unroll
        for (int j = 0; j < 4; j++) kr[j] = *(const bf16x8*)(src + j * 8);
        const u16* vsrc = vT + (size_t)(hh * 128 + vd) * MROWS + rowbase + kbase * 64 + vh;
#pragma unroll
        for (int j = 0; j < 4; j++) vr[j] = *(const bf16x8*)(vsrc + j * 8);
    }

#pragma unroll 1
    for (int t = 0; t < niter; ++t) {
        const int kt = kbase + t;
        __syncthreads();
#pragma unroll
        for (int j = 0; j < 4; j++) {
            int byteoff = sr * 256 + (sc + j * 8) * 2;
            *(bf16x8*)(sK + (byteoff ^ ((sr & 7) << 4))) = kr[j];
        }
#pragma unroll
        for (int j = 0; j < 4; j++) {
            int byteoff = vd * 128 + (vh + j * 8) * 2;
            *(bf16x8*)(sVt + (byteoff ^ ((vd & 7) << 4))) = vr[j];
        }
        __syncthreads();
        if (t + 1 < niter) {   // prefetch next tile into regs (hides under compute)
            const int krow = rowbase + (kt + 1) * 64 + sr;
            const u16* src = (sc < 64)
                ? kvbuf + (size_t)krow * 3072 + hh * 192 + sc
                : krbuf + (size_t)krow * 1024 + hh * 64 + (sc - 64);
#pragma unroll
            for (int j = 0; j < 4; j++) kr[j] = *(const bf16x8*)(src + j * 8);
            const u16* vsrc = vT + (size_t)(hh * 128 + vd) * MROWS + rowbase + (kt + 1) * 64 + vh;
#pragma unroll
            for (int j = 0; j < 4; j++) vr[j] = *(const bf16x8*)(vsrc + j * 8);
        }

        // wave-dead skip: this wave's q range is [q0+32w, q0+32w+31]
        const bool alive = (kt * 64) <= (q0 + w * 32 + 31);
        if (alive) {
            // QK^T swapped: A=K(32k x 16d), B=Q(16d x 32q) -> D[k][q], q=l31
            f32x16 scf[2];
#pragma unroll
            for (int b2 = 0; b2 < 2; b2++)
#pragma unroll
                for (int i = 0; i < 16; i++) scf[b2][i] = 0.f;
            __builtin_amdgcn_s_setprio(1);
#pragma unroll
            for (int s = 0; s < 8; s++) {
#pragma unroll
                for (int b2 = 0; b2 < 2; b2++) {
                    int krow = b2 * 32 + l31;
                    int kbyte = (krow * 256 + s * 32 + hx * 16) ^ ((l31 & 7) << 4);
                    bf16x8 kf = *(const bf16x8*)(sK + kbyte);
                    scf[b2] = __builtin_amdgcn_mfma_f32_32x32x16_bf16(kf, qf[s], scf[b2], 0, 0, 0);
                }
            }
            __builtin_amdgcn_s_setprio(0);

            // causal mask (only diagonal-adjacent tiles for this wave)
            if (kt * 64 + 63 > q0 + w * 32) {
                const int qg = q0 + w * 32 + l31;
#pragma unroll
                for (int b2 = 0; b2 < 2; b2++)
#pragma unroll
                    for (int rg = 0; rg < 16; rg++) {
                        int kg = kt * 64 + b2 * 32 + (rg & 3) + 8 * (rg >> 2) + 4 * hx;
                        if (kg > qg) scf[b2][rg] = -3e38f;
                    }
            }
            // online softmax: in-lane over 32 vals + partner exchange
            float mx = mi;
#pragma unroll
            for (int b2 = 0; b2 < 2; b2++)
#pragma unroll
                for (int rg = 0; rg < 16; rg++) mx = fmaxf(mx, scf[b2][rg]);
            mx = fmaxf(mx, __shfl_xor(mx, 32, 64));
            if (!__all(mx - mi <= THRR)) {   // T13 defer-max
                float f = exp2_fast((mi - mx) * C1);
                li *= f;
#pragma unroll
                for (int d = 0; d < 4; d++)
#pragma unroll
                    for (int i = 0; i < 16; i++) o[d][i] *= f;
                mi = mx;
            }
            float mc = mi * C1;
            float rs = 0.f;
#pragma unroll
            for (int b2 = 0; b2 < 2; b2++)
#pragma unroll
                for (int rg = 0; rg < 16; rg++) {
                    float pv = exp2_fast(__fmaf_rn(scf[b2][rg], C1, -mc));
                    scf[b2][rg] = pv;
                    rs += pv;
                }
            rs += __shfl_xor(rs, 32, 64);
            li += rs;

            // pack P -> bf16 pairs: pk[b][g] covers rows {8g..8g+3} + 4*hx
            u32 pk[2][4][2];
#pragma unroll
            for (int b2 = 0; b2 < 2; b2++)
#pragma unroll
                for (int g = 0; g < 4; g++) {
                    pk[b2][g][0] = (u32)f2bf(scf[b2][4 * g + 0]) | ((u32)f2bf(scf[b2][4 * g + 1]) << 16);
                    pk[b2][g][1] = (u32)f2bf(scf[b2][4 * g + 2]) | ((u32)f2bf(scf[b2][4 * g + 3]) << 16);
                }

            // PV swapped: A=V^T(32d x 16k), B=P^T(16k x 32q) -> O^T[d][q]
            __builtin_amdgcn_s_setprio(1);
#pragma unroll
            for (int t4 = 0; t4 < 4; t4++) {
                const int b2 = t4 >> 1, s = t4 & 1;
                // exchange with partner (lane^32): send the group partner needs
                u32 send0 = hx ? pk[b2][2 * s][0] : pk[b2][2 * s + 1][0];
                u32 send1 = hx ? pk[b2][2 * s][1] : pk[b2][2 * s + 1][1];
                u32 r0 = (u32)__shfl_xor((int)send0, 32, 64);
                u32 r1 = (u32)__shfl_xor((int)send1, 32, 64);
                union { u32 wd[4]; bf16x8 v; } pu;
                pu.wd[0] = hx ? r0 : pk[b2][2 * s][0];
                pu.wd[1] = hx ? r1 : pk[b2][2 * s][1];
                pu.wd[2] = hx ? pk[b2][2 * s + 1][0] : r0;
                pu.wd[3] = hx ? pk[b2][2 * s + 1][1] : r1;
#pragma unroll
                for (int dblk = 0; dblk < 4; dblk++) {
                    int vrow = dblk * 32 + l31;
                    int vbyte = (vrow * 128 + t4 * 32 + hx * 16) ^ ((l31 & 7) << 4);
                    bf16x8 vf = *(const bf16x8*)(sVt + vbyte);
                    o[dblk] = __builtin_amdgcn_mfma_f32_32x32x16_bf16(vf, pu.v, o[dblk], 0, 0, 0);
                }
            }
            __builtin_amdgcn_s_setprio(0);
        }
    }

    // ---- merge: group B publishes (m, l, O) via LDS; group A combines ----
    __syncthreads();   // all staging reads done; safe to overlay merge buffers
    if (grp) {
#pragma unroll
        for (int dblk = 0; dblk < 4; dblk++)
#pragma unroll
            for (int rg = 0; rg < 4; rg++) {
                int d0 = dblk * 32 + rg * 8 + hx * 4;
                f32x4 v;
                v[0] = o[dblk][rg * 4 + 0]; v[1] = o[dblk][rg * 4 + 1];
                v[2] = o[dblk][rg * 4 + 2]; v[3] = o[dblk][rg * 4 + 3];
                *(f32x4*)&mO[(w * 32 + l31) * 132 + d0] = v;
            }
        if (hx == 0) {
            mml[(w * 32 + l31) * 2 + 0] = mi;
            mml[(w * 32 + l31) * 2 + 1] = li;
        }
    }
    __syncthreads();
    if (!grp) {
        float mB = mml[(w * 32 + l31) * 2 + 0];
        float lB = mml[(w * 32 + l31) * 2 + 1];
        float m = fmaxf(mi, mB);
        float a0 = exp2_fast((mi - m) * C1);
        float a1 = exp2_fast((mB - m) * C1);
        float linv = 1.f / (li * a0 + lB * a1);
        u16* op = obuf + (size_t)(rowbase + q0 + w * 32 + l31) * 2048 + hh * 128;
#pragma unroll
        for (int dblk = 0; dblk < 4; dblk++)
#pragma unroll
            for (int rg = 0; rg < 4; rg++) {
                int d0 = dblk * 32 + rg * 8 + hx * 4;
                f32x4 ob = *(const f32x4*)&mO[(w * 32 + l31) * 132 + d0];
                ushort4 ov;
                ov.x = f2bf((o[dblk][rg * 4 + 0] * a0 + ob[0] * a1) * linv);
                ov.y = f2bf((o[dblk][rg * 4 + 1] * a0 + ob[1] * a1) * linv);
                ov.z = f2bf((o[dblk][rg * 4 + 2] * a0 + ob[2] * a1) * linv);
                ov.w = f2bf((o[dblk][rg * 4 + 3] * a0 + ob[3] * a1) * linv);
                *(ushort4*)(op + d0) = ov;
            }
    }
}

// ---------------- launch ----------------
extern "C" void kernel_launch(void* const* d_in, const int* in_sizes, int n_in,
                              void* d_out, int out_size, void* d_ws, size_t ws_size,
                              hipStream_t stream) {
    const float* x        = (const float*)d_in[0];
    const float* q_down_w = (const float*)d_in[1];
    const float* q_down_b = (const float*)d_in[2];
    const float* q_norm_w = (const float*)d_in[3];
    const float* q_up_w   = (const float*)d_in[4];
    const float* q_up_b   = (const float*)d_in[5];
    const float* kv_down_w= (const float*)d_in[6];
    const float* kv_down_b= (const float*)d_in[7];
    const float* kv_norm_w= (const float*)d_in[8];
    const float* kv_up_w  = (const float*)d_in[9];
    const float* kv_up_b  = (const float*)d_in[10];
    const float* k_rope_w = (const float*)d_in[11];
    const float* k_rope_b = (const float*)d_in[12];
    const float* out_w    = (const float*)d_in[13];
    const float* out_b    = (const float*)d_in[14];

    char* ws = (char*)d_ws;
    u16* xbf    = (u16*)(ws + 0);          // 16.78 MB ; later reused as vT
    u16* wcat   = (u16*)(ws + 16777216);   // 10.49 MB (2560x2048 bf16)
    u16* quw    = (u16*)(ws + 27262976);   // 4.19 MB
    u16* kvuw   = (u16*)(ws + 31457280);   // 3.15 MB
    u16* outw   = (u16*)(ws + 34603008);   // 8.39 MB
    float* bcat = (float*)(ws + 42991616); // 10 KB (pad to 16 KB)
    float* dcat = (float*)(ws + 43008000); // 25.17 MB (4096x1536 f32); reused as attnbuf
    u16* cq     = (u16*)(ws + 68173824);   // 8.39 MB
    u16* ckv    = (u16*)(ws + 76562432);   // 4.19 MB
    u16* qbuf   = (u16*)(ws + 80756736);   // 16.78 MB
    u16* kvbuf  = (u16*)(ws + 97533952);   // 25.17 MB
    u16* krbuf  = (u16*)(ws + 122699776);  // 8.39 MB  (end 131,088,384)
    u16* vT     = (u16*)(ws + 0);          // alias xbf (dead after gemm_down)
    u16* attnbuf= (u16*)(ws + 43008000);   // alias dcat (dead after rmsnorms)

    cvt_all<<<20992, 256, 0, stream>>>(
        x, xbf,
        q_down_w,  wcat,
        kv_down_w, wcat + 1024 * 2048,
        k_rope_w,  wcat + 1536 * 2048,
        q_up_w,    quw,
        kv_up_w,   kvuw,
        out_w,     outw);
    build_bcat<<<10, 256, 0, stream>>>(q_down_b, kv_down_b, k_rope_b, bcat);

    // fused down projections: x @ [q_down|kv_down|k_rope]^T
    gemm_down<<<dim3(20, 32), 256, 0, stream>>>(xbf, wcat, bcat, dcat, krbuf);
    rmsnorm_bf16<1024><<<MROWS, 256, 0, stream>>>(dcat, 1536, q_norm_w, cq);
    rmsnorm_bf16<512><<<MROWS, 256, 0, stream>>>(dcat + 1024, 1536, kv_norm_w, ckv);
    // up projections
    gemm_bt<u16><<<dim3(16, 32), 256, 0, stream>>>(cq, quw, q_up_b, qbuf, MROWS, 2048, 1024);
    gemm_bt<u16><<<dim3(24, 32), 256, 0, stream>>>(ckv, kvuw, kv_up_b, kvbuf, MROWS, 3072, 512);
    // V transpose (vT aliases xbf; xbf dead after gemm_down)
    transpose_v<<<dim3(64, 32), 256, 0, stream>>>(kvbuf, vT);
    // attention: 512 blocks x 512 threads, in-block K-split, 2 blocks/CU
    mla_attn<<<dim3(32, 16), 512, 0, stream>>>(qbuf, kvbuf, krbuf, vT, attnbuf);
    // output projection
    gemm_bt<float><<<dim3(16, 32), 256, 0, stream>>>(attnbuf, outw, out_b, (float*)d_out, MROWS, 2048, 2048);
}

// Round 13
// 264.545 us; speedup vs baseline: 1.6909x; 1.6909x over previous
//
#include <hip/hip_runtime.h>
#include <hip/hip_bf16.h>

typedef __attribute__((ext_vector_type(8))) short bf16x8;
typedef __attribute__((ext_vector_type(4))) float f32x4;
typedef __attribute__((ext_vector_type(16))) float f32x16;
typedef unsigned short u16;
typedef unsigned int u32;

#define RMS_EPS 1.1920929e-07f

constexpr int Bb = 2, Ss = 2048, DM = 2048, NH = 16;
constexpr int MROWS = Bb * Ss; // 4096

__device__ __forceinline__ u16 f2bf(float f) {
    __hip_bfloat16 h = __float2bfloat16(f);
    return *reinterpret_cast<u16*>(&h);
}

__device__ __forceinline__ float exp2_fast(float x) {
    float r; asm("v_exp_f32 %0, %1" : "=v"(r) : "v"(x)); return r;
}

__device__ __forceinline__ void gload16(const void* g, void* l) {
    __builtin_amdgcn_global_load_lds(
        (const __attribute__((address_space(1))) unsigned int*)g,
        (__attribute__((address_space(3))) unsigned int*)l, 16, 0, 0);
}

// ---------------- merged fp32 -> bf16 convert (7 segments, sizes fixed) -------
__global__ __launch_bounds__(256) void cvt_all(
    const float* __restrict__ s0, u16* __restrict__ d0,
    const float* __restrict__ s1, u16* __restrict__ d1,
    const float* __restrict__ s2, u16* __restrict__ d2,
    const float* __restrict__ s3, u16* __restrict__ d3,
    const float* __restrict__ s4, u16* __restrict__ d4,
    const float* __restrict__ s5, u16* __restrict__ d5,
    const float* __restrict__ s6, u16* __restrict__ d6)
{
    int i = blockIdx.x * 256 + threadIdx.x;   // float4 index; grid covers exactly 5373952
    const float* s; u16* d; int off;
    if (i < 2097152)      { s = s0; d = d0; off = 0; }
    else if (i < 2621440) { s = s1; d = d1; off = 2097152; }
    else if (i < 2883584) { s = s2; d = d2; off = 2621440; }
    else if (i < 3407872) { s = s3; d = d3; off = 2883584; }
    else if (i < 3932160) { s = s4; d = d4; off = 3407872; }
    else if (i < 4325376) { s = s5; d = d5; off = 3932160; }
    else                  { s = s6; d = d6; off = 4325376; }
    int j = i - off;
    float4 v = reinterpret_cast<const float4*>(s)[j];
    ushort4 o;
    o.x = f2bf(v.x); o.y = f2bf(v.y); o.z = f2bf(v.z); o.w = f2bf(v.w);
    reinterpret_cast<ushort4*>(d)[j] = o;
}

__global__ void build_bcat(const float* __restrict__ qb, const float* __restrict__ kvb,
                           const float* __restrict__ krb, float* __restrict__ bcat) {
    int i = blockIdx.x * 256 + threadIdx.x;
    if (i < 1024) bcat[i] = qb[i];
    else if (i < 1536) bcat[i] = kvb[i - 1024];
    else if (i < 2560) bcat[i] = krb[i - 1536];
}

// XCD-chunked bijective block remap (T1). Requires nwg % 8 == 0.
__device__ __forceinline__ void xcd_remap(int& bx, int& by) {
    int nx = gridDim.x, ny = gridDim.y;
    int nwg = nx * ny;
    if ((nwg & 7) != 0) return;
    int flat = blockIdx.x + nx * blockIdx.y;
    int chunk = nwg >> 3;
    int wg = (flat & 7) * chunk + (flat >> 3);
    by = wg % ny;          // M-tile fastest within an XCD chunk
    bx = wg / ny;          // few N-columns per XCD -> B-panel L2 reuse
}

// ---------------- GEMM: C(M,N) = A(M,K) * Bt(N,K)^T + bias ----------------
// 2-phase double-buffered: STAGE(t+1) issued BEFORE compute(t); 1 barrier/K-step.
template <typename OutT>
__global__ __launch_bounds__(256) void gemm_bt(
    const u16* __restrict__ A, const u16* __restrict__ Bt,
    const float* __restrict__ bias, OutT* __restrict__ C,
    int M, int N, int K)
{
    __shared__ alignas(16) u16 sA[2][128 * 32];
    __shared__ alignas(16) u16 sB[2][128 * 32];
    const int tid = threadIdx.x;
    const int lane = tid & 63;
    const int w = tid >> 6;
    const int wr = w >> 1, wc = w & 1;
    const int l16 = lane & 15, lq = lane >> 4;
    int bx = blockIdx.x, by = blockIdx.y;
    xcd_remap(bx, by);
    const int tileM = by * 128;
    const int tileN = bx * 128;

    f32x4 acc[4][4];
#pragma unroll
    for (int m = 0; m < 4; m++)
#pragma unroll
        for (int n = 0; n < 4; n++)
#pragma unroll
            for (int r = 0; r < 4; r++) acc[m][n][r] = 0.f;

    const int srow = w * 16 + (lane >> 2);
    const int scol = (lane & 3) * 8;
    const u16* gA0 = A + (size_t)(tileM + srow) * K + scol;
    const u16* gA1 = A + (size_t)(tileM + srow + 64) * K + scol;
    const u16* gB0 = Bt + (size_t)(tileN + srow) * K + scol;
    const u16* gB1 = Bt + (size_t)(tileN + srow + 64) * K + scol;
    u16* lA0 = &sA[0][0] + w * 512;
    u16* lA1 = &sA[0][0] + 2048 + w * 512;
    u16* lB0 = &sB[0][0] + w * 512;
    u16* lB1 = &sB[0][0] + 2048 + w * 512;

    int aoff[4], boff[4];
#pragma unroll
    for (int m = 0; m < 4; m++) aoff[m] = (wr * 64 + m * 16 + l16) * 32 + lq * 8;
#pragma unroll
    for (int n = 0; n < 4; n++) boff[n] = (wc * 64 + n * 16 + l16) * 32 + lq * 8;

    const int nk = K >> 5;
    // prologue: stage tile 0 into buffer 0
    gload16(gA0, lA0);
    gload16(gA1, lA1);
    gload16(gB0, lB0);
    gload16(gB1, lB1);
    __syncthreads();
    int cur = 0;
    for (int kk = 0; kk < nk; ++kk) {
        if (kk + 1 < nk) {   // issue next-tile DMA into other buffer (overlaps compute)
            int nb = (cur ^ 1) * 4096;
            const u16* a0 = gA0 + (size_t)(kk + 1) * 32;
            const u16* a1 = gA1 + (size_t)(kk + 1) * 32;
            const u16* b0 = gB0 + (size_t)(kk + 1) * 32;
            const u16* b1 = gB1 + (size_t)(kk + 1) * 32;
            gload16(a0, lA0 + nb);
            gload16(a1, lA1 + nb);
            gload16(b0, lB0 + nb);
            gload16(b1, lB1 + nb);
        }
        const u16* bA = &sA[0][0] + cur * 4096;
        const u16* bB = &sB[0][0] + cur * 4096;
        bf16x8 af[4], bfr[4];
#pragma unroll
        for (int m = 0; m < 4; m++) af[m] = *(const bf16x8*)&bA[aoff[m]];
#pragma unroll
        for (int n = 0; n < 4; n++) bfr[n] = *(const bf16x8*)&bB[boff[n]];
        __builtin_amdgcn_s_setprio(1);
#pragma unroll
        for (int m = 0; m < 4; m++)
#pragma unroll
            for (int n = 0; n < 4; n++)
                acc[m][n] = __builtin_amdgcn_mfma_f32_16x16x32_bf16(af[m], bfr[n], acc[m][n], 0, 0, 0);
        __builtin_amdgcn_s_setprio(0);
        __syncthreads();   // drains staged DMA (had full compute phase to land) + read-done
        cur ^= 1;
    }

#pragma unroll
    for (int n = 0; n < 4; n++) {
        int col = tileN + wc * 64 + n * 16 + l16;
        float bv = bias ? bias[col] : 0.f;
#pragma unroll
        for (int m = 0; m < 4; m++) {
            int rowb = tileM + wr * 64 + m * 16 + (lq << 2);
#pragma unroll
            for (int r = 0; r < 4; r++) {
                float v = acc[m][n][r] + bv;
                if constexpr (sizeof(OutT) == 2)
                    C[(size_t)(rowb + r) * N + col] = (OutT)f2bf(v);
                else
                    C[(size_t)(rowb + r) * N + col] = (OutT)v;
            }
        }
    }
}

// ---------------- fused down-proj GEMM: N=2560 (1024 q | 512 kv | 1024 rope) ----
// Same 2-phase schedule as gemm_bt.
__global__ __launch_bounds__(256) void gemm_down(
    const u16* __restrict__ A, const u16* __restrict__ Bt,
    const float* __restrict__ bcat, float* __restrict__ dcat,
    u16* __restrict__ krbuf)
{
    constexpr int K = 2048;
    __shared__ alignas(16) u16 sA[2][128 * 32];
    __shared__ alignas(16) u16 sB[2][128 * 32];
    const int tid = threadIdx.x;
    const int lane = tid & 63;
    const int w = tid >> 6;
    const int wr = w >> 1, wc = w & 1;
    const int l16 = lane & 15, lq = lane >> 4;
    int bx = blockIdx.x, by = blockIdx.y;
    xcd_remap(bx, by);
    const int tileM = by * 128;
    const int tileN = bx * 128;

    f32x4 acc[4][4];
#pragma unroll
    for (int m = 0; m < 4; m++)
#pragma unroll
        for (int n = 0; n < 4; n++)
#pragma unroll
            for (int r = 0; r < 4; r++) acc[m][n][r] = 0.f;

    const int srow = w * 16 + (lane >> 2);
    const int scol = (lane & 3) * 8;
    const u16* gA0 = A + (size_t)(tileM + srow) * K + scol;
    const u16* gA1 = A + (size_t)(tileM + srow + 64) * K + scol;
    const u16* gB0 = Bt + (size_t)(tileN + srow) * K + scol;
    const u16* gB1 = Bt + (size_t)(tileN + srow + 64) * K + scol;
    u16* lA0 = &sA[0][0] + w * 512;
    u16* lA1 = &sA[0][0] + 2048 + w * 512;
    u16* lB0 = &sB[0][0] + w * 512;
    u16* lB1 = &sB[0][0] + 2048 + w * 512;

    int aoff[4], boff[4];
#pragma unroll
    for (int m = 0; m < 4; m++) aoff[m] = (wr * 64 + m * 16 + l16) * 32 + lq * 8;
#pragma unroll
    for (int n = 0; n < 4; n++) boff[n] = (wc * 64 + n * 16 + l16) * 32 + lq * 8;

    const int nk = K >> 5;
    gload16(gA0, lA0);
    gload16(gA1, lA1);
    gload16(gB0, lB0);
    gload16(gB1, lB1);
    __syncthreads();
    int cur = 0;
    for (int kk = 0; kk < nk; ++kk) {
        if (kk + 1 < nk) {
            int nb = (cur ^ 1) * 4096;
            const u16* a0 = gA0 + (size_t)(kk + 1) * 32;
            const u16* a1 = gA1 + (size_t)(kk + 1) * 32;
            const u16* b0 = gB0 + (size_t)(kk + 1) * 32;
            const u16* b1 = gB1 + (size_t)(kk + 1) * 32;
            gload16(a0, lA0 + nb);
            gload16(a1, lA1 + nb);
            gload16(b0, lB0 + nb);
            gload16(b1, lB1 + nb);
        }
        const u16* bA = &sA[0][0] + cur * 4096;
        const u16* bB = &sB[0][0] + cur * 4096;
        bf16x8 af[4], bfr[4];
#pragma unroll
        for (int m = 0; m < 4; m++) af[m] = *(const bf16x8*)&bA[aoff[m]];
#pragma unroll
        for (int n = 0; n < 4; n++) bfr[n] = *(const bf16x8*)&bB[boff[n]];
        __builtin_amdgcn_s_setprio(1);
#pragma unroll
        for (int m = 0; m < 4; m++)
#pragma unroll
            for (int n = 0; n < 4; n++)
                acc[m][n] = __builtin_amdgcn_mfma_f32_16x16x32_bf16(af[m], bfr[n], acc[m][n], 0, 0, 0);
        __builtin_amdgcn_s_setprio(0);
        __syncthreads();
        cur ^= 1;
    }

    const bool isrope = (tileN >= 1536);
#pragma unroll
    for (int n = 0; n < 4; n++) {
        int col = tileN + wc * 64 + n * 16 + l16;
        float bv = bcat[col];
#pragma unroll
        for (int m = 0; m < 4; m++) {
            int rowb = tileM + wr * 64 + m * 16 + (lq << 2);
#pragma unroll
            for (int r = 0; r < 4; r++) {
                float v = acc[m][n][r] + bv;
                if (!isrope) dcat[(size_t)(rowb + r) * 1536 + col] = v;
                else         krbuf[(size_t)(rowb + r) * 1024 + (col - 1536)] = f2bf(v);
            }
        }
    }
}

// ---------------- RMS norm (row-wise, strided in), fp32 in -> bf16 out --------
template <int C>
__global__ __launch_bounds__(256) void rmsnorm_bf16(
    const float* __restrict__ in, int istride, const float* __restrict__ wgt, u16* __restrict__ out)
{
    const int row = blockIdx.x;
    const int tid = threadIdx.x;
    constexpr int PER = C / 256;
    const float* p = in + (size_t)row * istride;
    float v[PER];
    float ss = 0.f;
#pragma unroll
    for (int i = 0; i < PER; i++) { v[i] = p[tid + i * 256]; ss += v[i] * v[i]; }
#pragma unroll
    for (int o = 32; o; o >>= 1) ss += __shfl_xor(ss, o, 64);
    __shared__ float red[4];
    if ((tid & 63) == 0) red[tid >> 6] = ss;
    __syncthreads();
    float tot = red[0] + red[1] + red[2] + red[3];
    float inv = rsqrtf(tot / (float)C + RMS_EPS);
    u16* q = out + (size_t)row * C;
#pragma unroll
    for (int i = 0; i < PER; i++) {
        int c = tid + i * 256;
        q[c] = f2bf(v[i] * inv * wgt[c]);
    }
}

// ---------------- V transpose: kvbuf[token][h*192+64+d] -> vT[(h*128+d)*4096+token]
__global__ __launch_bounds__(256) void transpose_v(
    const u16* __restrict__ kvbuf, u16* __restrict__ vT)
{
    __shared__ alignas(16) u16 tile[64][72];
    const int tid = threadIdx.x;
    const int t0 = blockIdx.x * 64;
    const int h = blockIdx.y >> 1, dh = blockIdx.y & 1;
    const int trow = tid >> 2, c8 = (tid & 3) * 8;
    const u16* src = kvbuf + (size_t)(t0 + trow) * 3072 + h * 192 + 64 + dh * 64 + c8;
    *(bf16x8*)&tile[trow][c8]      = *(const bf16x8*)src;
    *(bf16x8*)&tile[trow][c8 + 32] = *(const bf16x8*)(src + 32);
    __syncthreads();
    const int drow = tid >> 2, tc8 = (tid & 3) * 8;
    bf16x8 a, b2;
#pragma unroll
    for (int j = 0; j < 8; j++) {
        a[j]  = (short)tile[tc8 + j][drow];
        b2[j] = (short)tile[tc8 + 32 + j][drow];
    }
    u16* dst = vT + (size_t)(h * 128 + dh * 64 + drow) * MROWS + t0 + tc8;
    *(bf16x8*)dst = a;
    *(bf16x8*)(dst + 32) = b2;
}

// ---------------- causal flash attention, 32x32 MFMA, 32 q/wave (round-8) ----
// QBLK=128 (4 waves x 32 q), KT=64. Grid (32 bh, 16 y); qt = jj? 15-2*ii : 2*ii
// -> co-resident pairs (qt, 15-qt) give every CU exactly 34 k-tiles.
// Swapped mfma(K,Q): lane = q-column (lane&31); lane and lane^32 hold
// complementary k-row halves -> softmax reduce = in-lane + 1 shfl_xor(32).
// P repacked in-register (16 packs + 8 shfl) -> NO P LDS, no extra barrier.
// LDS = 32 KB (sK 64x128 + sVt 128x64), 2 blocks/CU.
__global__ __launch_bounds__(256, 2) void mla_attn(
    const u16* __restrict__ qbuf,   // (4096, 2048) head-major h*128
    const u16* __restrict__ kvbuf,  // (4096, 3072) per head 192: knope(64) v(128)
    const u16* __restrict__ krbuf,  // (4096, 1024) per head 64
    const u16* __restrict__ vT,     // (h*128+d, 4096 tokens)
    u16* __restrict__ obuf)         // (4096, 2048)
{
    const int bh = blockIdx.x;
    const int y = blockIdx.y;
    const int ii = y & 7, jj = y >> 3;
    const int qt = jj ? (15 - 2 * ii) : (2 * ii);
    const int b = bh >> 4, hh = bh & 15;
    const int tid = threadIdx.x, lane = tid & 63, w = tid >> 6;
    const int l31 = lane & 31, hx = lane >> 5;

    __shared__ alignas(16) u16 sK[64 * 128];
    __shared__ alignas(16) u16 sVt[128 * 64];

    const int rowbase = b * Ss;
    const int q0 = qt * 128;
    const int nkt = 2 * qt + 2;

    const int sr = tid >> 2, sc = (tid & 3) * 32;   // K staging
    const int vd = tid >> 1, vh = (tid & 1) * 32;   // V staging
    const float C1 = 0.12751742f;    // softmax_scale * log2(e)
    const float THRR = 90.5f;        // defer-max threshold (raw score units)

    // Q fragments: lane (q=l31, hx) needs d-chunks (2c + hx), c = 0..7
    bf16x8 qf[8];
    {
        const u16* qp = qbuf + (size_t)(rowbase + q0 + w * 32 + l31) * 2048 + hh * 128;
#pragma unroll
        for (int c = 0; c < 8; c++) qf[c] = *(const bf16x8*)(qp + (2 * c + hx) * 8);
    }
    float mi = -3e38f, li = 0.f;
    f32x16 o[4];
#pragma unroll
    for (int d = 0; d < 4; d++)
#pragma unroll
        for (int i = 0; i < 16; i++) o[d][i] = 0.f;

    bf16x8 kr[4], vr[4];
    {   // prologue: tile 0 -> regs
        const int krow = rowbase + sr;
        const u16* src = (sc < 64)
            ? kvbuf + (size_t)krow * 3072 + hh * 192 + sc
            : krbuf + (size_t)krow * 1024 + hh * 64 + (sc - 64);
#pragma unroll
        for (int j = 0; j < 4; j++) kr[j] = *(const bf16x8*)(src + j * 8);
        const u16* vsrc = vT + (size_t)(hh * 128 + vd) * MROWS + rowbase + vh;
#pragma unroll
        for (int j = 0; j < 4; j++) vr[j] = *(const bf16x8*)(vsrc + j * 8);
    }

#pragma unroll 1
    for (int kt = 0; kt < nkt; ++kt) {
        __syncthreads();
#pragma unroll
        for (int j = 0; j < 4; j++) {
            int byteoff = sr * 256 + (sc + j * 8) * 2;
            *(bf16x8*)((char*)sK + (byteoff ^ ((sr & 7) << 4))) = kr[j];
        }
#pragma unroll
        for (int j = 0; j < 4; j++) {
            int byteoff = vd * 128 + (vh + j * 8) * 2;
            *(bf16x8*)((char*)sVt + (byteoff ^ ((vd & 7) << 4))) = vr[j];
        }
        __syncthreads();
        if (kt + 1 < nkt) {   // prefetch next tile into regs (hides under compute)
            const int krow = rowbase + (kt + 1) * 64 + sr;
            const u16* src = (sc < 64)
                ? kvbuf + (size_t)krow * 3072 + hh * 192 + sc
                : krbuf + (size_t)krow * 1024 + hh * 64 + (sc - 64);
#pragma unroll
            for (int j = 0; j < 4; j++) kr[j] = *(const bf16x8*)(src + j * 8);
            const u16* vsrc = vT + (size_t)(hh * 128 + vd) * MROWS + rowbase + (kt + 1) * 64 + vh;
#pragma unroll
            for (int j = 0; j < 4; j++) vr[j] = *(const bf16x8*)(vsrc + j * 8);
        }

        // wave-dead skip: this wave's q range is [q0+32w, q0+32w+31]
        const bool alive = (kt * 64) <= (q0 + w * 32 + 31);
        if (alive) {
            // QK^T swapped: A=K(32k x 16d), B=Q(16d x 32q) -> D[k][q], q=l31
            f32x16 scf[2];
#pragma unroll
            for (int b2 = 0; b2 < 2; b2++)
#pragma unroll
                for (int i = 0; i < 16; i++) scf[b2][i] = 0.f;
            __builtin_amdgcn_s_setprio(1);
#pragma unroll
            for (int s = 0; s < 8; s++) {
#pragma unroll
                for (int b2 = 0; b2 < 2; b2++) {
                    int krow = b2 * 32 + l31;
                    int kbyte = (krow * 256 + s * 32 + hx * 16) ^ ((l31 & 7) << 4);
                    bf16x8 kf = *(const bf16x8*)((char*)sK + kbyte);
                    scf[b2] = __builtin_amdgcn_mfma_f32_32x32x16_bf16(kf, qf[s], scf[b2], 0, 0, 0);
                }
            }
            __builtin_amdgcn_s_setprio(0);

            // causal mask (only diagonal-adjacent tiles for this wave)
            if (kt * 64 + 63 > q0 + w * 32) {
                const int qg = q0 + w * 32 + l31;
#pragma unroll
                for (int b2 = 0; b2 < 2; b2++)
#pragma unroll
                    for (int rg = 0; rg < 16; rg++) {
                        int kg = kt * 64 + b2 * 32 + (rg & 3) + 8 * (rg >> 2) + 4 * hx;
                        if (kg > qg) scf[b2][rg] = -3e38f;
                    }
            }
            // online softmax: in-lane over 32 vals + partner exchange
            float mx = mi;
#pragma unroll
            for (int b2 = 0; b2 < 2; b2++)
#pragma unroll
                for (int rg = 0; rg < 16; rg++) mx = fmaxf(mx, scf[b2][rg]);
            mx = fmaxf(mx, __shfl_xor(mx, 32, 64));
            if (!__all(mx - mi <= THRR)) {   // T13 defer-max
                float f = exp2_fast((mi - mx) * C1);
                li *= f;
#pragma unroll
                for (int d = 0; d < 4; d++)
#pragma unroll
                    for (int i = 0; i < 16; i++) o[d][i] *= f;
                mi = mx;
            }
            float mc = mi * C1;
            float rs = 0.f;
#pragma unroll
            for (int b2 = 0; b2 < 2; b2++)
#pragma unroll
                for (int rg = 0; rg < 16; rg++) {
                    float pv = exp2_fast(__fmaf_rn(scf[b2][rg], C1, -mc));
                    scf[b2][rg] = pv;
                    rs += pv;
                }
            rs += __shfl_xor(rs, 32, 64);
            li += rs;

            // pack P -> bf16 pairs: pk[b][g] covers rows {8g..8g+3} + 4*hx
            u32 pk[2][4][2];
#pragma unroll
            for (int b2 = 0; b2 < 2; b2++)
#pragma unroll
                for (int g = 0; g < 4; g++) {
                    pk[b2][g][0] = (u32)f2bf(scf[b2][4 * g + 0]) | ((u32)f2bf(scf[b2][4 * g + 1]) << 16);
                    pk[b2][g][1] = (u32)f2bf(scf[b2][4 * g + 2]) | ((u32)f2bf(scf[b2][4 * g + 3]) << 16);
                }

            // PV swapped: A=V^T(32d x 16k), B=P^T(16k x 32q) -> O^T[d][q]
            __builtin_amdgcn_s_setprio(1);
#pragma unroll
            for (int t = 0; t < 4; t++) {
                const int b2 = t >> 1, s = t & 1;
                // exchange with partner (lane^32): send the group partner needs
                u32 send0 = hx ? pk[b2][2 * s][0] : pk[b2][2 * s + 1][0];
                u32 send1 = hx ? pk[b2][2 * s][1] : pk[b2][2 * s + 1][1];
                u32 r0 = (u32)__shfl_xor((int)send0, 32, 64);
                u32 r1 = (u32)__shfl_xor((int)send1, 32, 64);
                union { u32 wd[4]; bf16x8 v; } pu;
                pu.wd[0] = hx ? r0 : pk[b2][2 * s][0];
                pu.wd[1] = hx ? r1 : pk[b2][2 * s][1];
                pu.wd[2] = hx ? pk[b2][2 * s + 1][0] : r0;
                pu.wd[3] = hx ? pk[b2][2 * s + 1][1] : r1;
#pragma unroll
                for (int dblk = 0; dblk < 4; dblk++) {
                    int vrow = dblk * 32 + l31;
                    int vbyte = (vrow * 128 + t * 32 + hx * 16) ^ ((l31 & 7) << 4);
                    bf16x8 vf = *(const bf16x8*)((char*)sVt + vbyte);
                    o[dblk] = __builtin_amdgcn_mfma_f32_32x32x16_bf16(vf, pu.v, o[dblk], 0, 0, 0);
                }
            }
            __builtin_amdgcn_s_setprio(0);
        }
    }
    // epilogue: lane holds O^T[d][q=l31]; d = 32*dblk + 8*rg + 4*hx + a
    float invl = 1.f / li;
    u16* op = obuf + (size_t)(rowbase + q0 + w * 32 + l31) * 2048 + hh * 128;
#pragma unroll
    for (int dblk = 0; dblk < 4; dblk++)
#pragma unroll
        for (int rg = 0; rg < 4; rg++) {
            int d0 = dblk * 32 + rg * 8 + hx * 4;
            ushort4 ov;
            ov.x = f2bf(o[dblk][rg * 4 + 0] * invl);
            ov.y = f2bf(o[dblk][rg * 4 + 1] * invl);
            ov.z = f2bf(o[dblk][rg * 4 + 2] * invl);
            ov.w = f2bf(o[dblk][rg * 4 + 3] * invl);
            *(ushort4*)(op + d0) = ov;
        }
}

// ---------------- launch ----------------
extern "C" void kernel_launch(void* const* d_in, const int* in_sizes, int n_in,
                              void* d_out, int out_size, void* d_ws, size_t ws_size,
                              hipStream_t stream) {
    const float* x        = (const float*)d_in[0];
    const float* q_down_w = (const float*)d_in[1];
    const float* q_down_b = (const float*)d_in[2];
    const float* q_norm_w = (const float*)d_in[3];
    const float* q_up_w   = (const float*)d_in[4];
    const float* q_up_b   = (const float*)d_in[5];
    const float* kv_down_w= (const float*)d_in[6];
    const float* kv_down_b= (const float*)d_in[7];
    const float* kv_norm_w= (const float*)d_in[8];
    const float* kv_up_w  = (const float*)d_in[9];
    const float* kv_up_b  = (const float*)d_in[10];
    const float* k_rope_w = (const float*)d_in[11];
    const float* k_rope_b = (const float*)d_in[12];
    const float* out_w    = (const float*)d_in[13];
    const float* out_b    = (const float*)d_in[14];

    char* ws = (char*)d_ws;
    u16* xbf    = (u16*)(ws + 0);          // 16.78 MB ; later reused as vT
    u16* wcat   = (u16*)(ws + 16777216);   // 10.49 MB (2560x2048 bf16)
    u16* quw    = (u16*)(ws + 27262976);   // 4.19 MB
    u16* kvuw   = (u16*)(ws + 31457280);   // 3.15 MB
    u16* outw   = (u16*)(ws + 34603008);   // 8.39 MB
    float* bcat = (float*)(ws + 42991616); // 10 KB (pad to 16 KB)
    float* dcat = (float*)(ws + 43008000); // 25.17 MB (4096x1536 f32); reused as attnbuf
    u16* cq     = (u16*)(ws + 68173824);   // 8.39 MB
    u16* ckv    = (u16*)(ws + 76562432);   // 4.19 MB
    u16* qbuf   = (u16*)(ws + 80756736);   // 16.78 MB
    u16* kvbuf  = (u16*)(ws + 97533952);   // 25.17 MB
    u16* krbuf  = (u16*)(ws + 122699776);  // 8.39 MB  (end 131,088,384)
    u16* vT     = (u16*)(ws + 0);          // alias xbf (dead after gemm_down)
    u16* attnbuf= (u16*)(ws + 43008000);   // alias dcat (dead after rmsnorms)

    cvt_all<<<20992, 256, 0, stream>>>(
        x, xbf,
        q_down_w,  wcat,
        kv_down_w, wcat + 1024 * 2048,
        k_rope_w,  wcat + 1536 * 2048,
        q_up_w,    quw,
        kv_up_w,   kvuw,
        out_w,     outw);
    build_bcat<<<10, 256, 0, stream>>>(q_down_b, kv_down_b, k_rope_b, bcat);

    // fused down projections: x @ [q_down|kv_down|k_rope]^T
    gemm_down<<<dim3(20, 32), 256, 0, stream>>>(xbf, wcat, bcat, dcat, krbuf);
    rmsnorm_bf16<1024><<<MROWS, 256, 0, stream>>>(dcat, 1536, q_norm_w, cq);
    rmsnorm_bf16<512><<<MROWS, 256, 0, stream>>>(dcat + 1024, 1536, kv_norm_w, ckv);
    // up projections
    gemm_bt<u16><<<dim3(16, 32), 256, 0, stream>>>(cq, quw, q_up_b, qbuf, MROWS, 2048, 1024);
    gemm_bt<u16><<<dim3(24, 32), 256, 0, stream>>>(ckv, kvuw, kv_up_b, kvbuf, MROWS, 3072, 512);
    // V transpose (vT aliases xbf; xbf dead after gemm_down)
    transpose_v<<<dim3(64, 32), 256, 0, stream>>>(kvbuf, vT);
    // attention: 512 blocks (32 bh x 16 qt balanced-paired), 2 blocks/CU
    mla_attn<<<dim3(32, 16), 256, 0, stream>>>(qbuf, kvbuf, krbuf, vT, attnbuf);
    // output projection
    gemm_bt<float><<<dim3(16, 32), 256, 0, stream>>>(attnbuf, outw, out_b, (float*)d_out, MROWS, 2048, 2048);
}

// Round 14
// 259.953 us; speedup vs baseline: 1.7208x; 1.0177x over previous
//
#include <hip/hip_runtime.h>
#include <hip/hip_bf16.h>

typedef __attribute__((ext_vector_type(8))) short bf16x8;
typedef __attribute__((ext_vector_type(4))) float f32x4;
typedef __attribute__((ext_vector_type(16))) float f32x16;
typedef unsigned short u16;
typedef unsigned int u32;

#define RMS_EPS 1.1920929e-07f

constexpr int Bb = 2, Ss = 2048, DM = 2048, NH = 16;
constexpr int MROWS = Bb * Ss; // 4096

__device__ __forceinline__ u16 f2bf(float f) {
    __hip_bfloat16 h = __float2bfloat16(f);
    return *reinterpret_cast<u16*>(&h);
}

__device__ __forceinline__ float exp2_fast(float x) {
    float r; asm("v_exp_f32 %0, %1" : "=v"(r) : "v"(x)); return r;
}

__device__ __forceinline__ void gload16(const void* g, void* l) {
    __builtin_amdgcn_global_load_lds(
        (const __attribute__((address_space(1))) unsigned int*)g,
        (__attribute__((address_space(3))) unsigned int*)l, 16, 0, 0);
}

// ---------------- merged fp32 -> bf16 convert (7 segments, sizes fixed) -------
__global__ __launch_bounds__(256) void cvt_all(
    const float* __restrict__ s0, u16* __restrict__ d0,
    const float* __restrict__ s1, u16* __restrict__ d1,
    const float* __restrict__ s2, u16* __restrict__ d2,
    const float* __restrict__ s3, u16* __restrict__ d3,
    const float* __restrict__ s4, u16* __restrict__ d4,
    const float* __restrict__ s5, u16* __restrict__ d5,
    const float* __restrict__ s6, u16* __restrict__ d6)
{
    int i = blockIdx.x * 256 + threadIdx.x;   // float4 index; grid covers exactly 5373952
    const float* s; u16* d; int off;
    if (i < 2097152)      { s = s0; d = d0; off = 0; }
    else if (i < 2621440) { s = s1; d = d1; off = 2097152; }
    else if (i < 2883584) { s = s2; d = d2; off = 2621440; }
    else if (i < 3407872) { s = s3; d = d3; off = 2883584; }
    else if (i < 3932160) { s = s4; d = d4; off = 3407872; }
    else if (i < 4325376) { s = s5; d = d5; off = 3932160; }
    else                  { s = s6; d = d6; off = 4325376; }
    int j = i - off;
    float4 v = reinterpret_cast<const float4*>(s)[j];
    ushort4 o;
    o.x = f2bf(v.x); o.y = f2bf(v.y); o.z = f2bf(v.z); o.w = f2bf(v.w);
    reinterpret_cast<ushort4*>(d)[j] = o;
}

__global__ void build_bcat(const float* __restrict__ qb, const float* __restrict__ kvb,
                           const float* __restrict__ krb, float* __restrict__ bcat) {
    int i = blockIdx.x * 256 + threadIdx.x;
    if (i < 1024) bcat[i] = qb[i];
    else if (i < 1536) bcat[i] = kvb[i - 1024];
    else if (i < 2560) bcat[i] = krb[i - 1536];
}

// XCD-chunked bijective block remap (T1). Requires nwg % 8 == 0.
__device__ __forceinline__ void xcd_remap(int& bx, int& by) {
    int nx = gridDim.x, ny = gridDim.y;
    int nwg = nx * ny;
    if ((nwg & 7) != 0) return;
    int flat = blockIdx.x + nx * blockIdx.y;
    int chunk = nwg >> 3;
    int wg = (flat & 7) * chunk + (flat >> 3);
    by = wg % ny;          // M-tile fastest within an XCD chunk
    bx = wg / ny;          // few N-columns per XCD -> B-panel L2 reuse
}

// ---------------- GEMM: C(M,N) = A(M,K) * Bt(N,K)^T + bias ----------------
// 2-phase double-buffered: STAGE(t+1) issued BEFORE compute(t); 1 barrier/K-step.
template <typename OutT>
__global__ __launch_bounds__(256) void gemm_bt(
    const u16* __restrict__ A, const u16* __restrict__ Bt,
    const float* __restrict__ bias, OutT* __restrict__ C,
    int M, int N, int K)
{
    __shared__ alignas(16) u16 sA[2][128 * 32];
    __shared__ alignas(16) u16 sB[2][128 * 32];
    const int tid = threadIdx.x;
    const int lane = tid & 63;
    const int w = tid >> 6;
    const int wr = w >> 1, wc = w & 1;
    const int l16 = lane & 15, lq = lane >> 4;
    int bx = blockIdx.x, by = blockIdx.y;
    xcd_remap(bx, by);
    const int tileM = by * 128;
    const int tileN = bx * 128;

    f32x4 acc[4][4];
#pragma unroll
    for (int m = 0; m < 4; m++)
#pragma unroll
        for (int n = 0; n < 4; n++)
#pragma unroll
            for (int r = 0; r < 4; r++) acc[m][n][r] = 0.f;

    const int srow = w * 16 + (lane >> 2);
    const int scol = (lane & 3) * 8;
    const u16* gA0 = A + (size_t)(tileM + srow) * K + scol;
    const u16* gA1 = A + (size_t)(tileM + srow + 64) * K + scol;
    const u16* gB0 = Bt + (size_t)(tileN + srow) * K + scol;
    const u16* gB1 = Bt + (size_t)(tileN + srow + 64) * K + scol;
    u16* lA0 = &sA[0][0] + w * 512;
    u16* lA1 = &sA[0][0] + 2048 + w * 512;
    u16* lB0 = &sB[0][0] + w * 512;
    u16* lB1 = &sB[0][0] + 2048 + w * 512;

    int aoff[4], boff[4];
#pragma unroll
    for (int m = 0; m < 4; m++) aoff[m] = (wr * 64 + m * 16 + l16) * 32 + lq * 8;
#pragma unroll
    for (int n = 0; n < 4; n++) boff[n] = (wc * 64 + n * 16 + l16) * 32 + lq * 8;

    const int nk = K >> 5;
    // prologue: stage tile 0 into buffer 0
    gload16(gA0, lA0);
    gload16(gA1, lA1);
    gload16(gB0, lB0);
    gload16(gB1, lB1);
    __syncthreads();
    int cur = 0;
    for (int kk = 0; kk < nk; ++kk) {
        if (kk + 1 < nk) {   // issue next-tile DMA into other buffer (overlaps compute)
            int nb = (cur ^ 1) * 4096;
            const u16* a0 = gA0 + (size_t)(kk + 1) * 32;
            const u16* a1 = gA1 + (size_t)(kk + 1) * 32;
            const u16* b0 = gB0 + (size_t)(kk + 1) * 32;
            const u16* b1 = gB1 + (size_t)(kk + 1) * 32;
            gload16(a0, lA0 + nb);
            gload16(a1, lA1 + nb);
            gload16(b0, lB0 + nb);
            gload16(b1, lB1 + nb);
        }
        const u16* bA = &sA[0][0] + cur * 4096;
        const u16* bB = &sB[0][0] + cur * 4096;
        bf16x8 af[4], bfr[4];
#pragma unroll
        for (int m = 0; m < 4; m++) af[m] = *(const bf16x8*)&bA[aoff[m]];
#pragma unroll
        for (int n = 0; n < 4; n++) bfr[n] = *(const bf16x8*)&bB[boff[n]];
        __builtin_amdgcn_s_setprio(1);
#pragma unroll
        for (int m = 0; m < 4; m++)
#pragma unroll
            for (int n = 0; n < 4; n++)
                acc[m][n] = __builtin_amdgcn_mfma_f32_16x16x32_bf16(af[m], bfr[n], acc[m][n], 0, 0, 0);
        __builtin_amdgcn_s_setprio(0);
        __syncthreads();   // drains staged DMA (had full compute phase to land) + read-done
        cur ^= 1;
    }

#pragma unroll
    for (int n = 0; n < 4; n++) {
        int col = tileN + wc * 64 + n * 16 + l16;
        float bv = bias ? bias[col] : 0.f;
#pragma unroll
        for (int m = 0; m < 4; m++) {
            int rowb = tileM + wr * 64 + m * 16 + (lq << 2);
#pragma unroll
            for (int r = 0; r < 4; r++) {
                float v = acc[m][n][r] + bv;
                if constexpr (sizeof(OutT) == 2)
                    C[(size_t)(rowb + r) * N + col] = (OutT)f2bf(v);
                else
                    C[(size_t)(rowb + r) * N + col] = (OutT)v;
            }
        }
    }
}

// ---------------- fused down-proj GEMM: N=2560 (1024 q | 512 kv | 1024 rope) ----
// Same 2-phase schedule as gemm_bt.
__global__ __launch_bounds__(256) void gemm_down(
    const u16* __restrict__ A, const u16* __restrict__ Bt,
    const float* __restrict__ bcat, float* __restrict__ dcat,
    u16* __restrict__ krbuf)
{
    constexpr int K = 2048;
    __shared__ alignas(16) u16 sA[2][128 * 32];
    __shared__ alignas(16) u16 sB[2][128 * 32];
    const int tid = threadIdx.x;
    const int lane = tid & 63;
    const int w = tid >> 6;
    const int wr = w >> 1, wc = w & 1;
    const int l16 = lane & 15, lq = lane >> 4;
    int bx = blockIdx.x, by = blockIdx.y;
    xcd_remap(bx, by);
    const int tileM = by * 128;
    const int tileN = bx * 128;

    f32x4 acc[4][4];
#pragma unroll
    for (int m = 0; m < 4; m++)
#pragma unroll
        for (int n = 0; n < 4; n++)
#pragma unroll
            for (int r = 0; r < 4; r++) acc[m][n][r] = 0.f;

    const int srow = w * 16 + (lane >> 2);
    const int scol = (lane & 3) * 8;
    const u16* gA0 = A + (size_t)(tileM + srow) * K + scol;
    const u16* gA1 = A + (size_t)(tileM + srow + 64) * K + scol;
    const u16* gB0 = Bt + (size_t)(tileN + srow) * K + scol;
    const u16* gB1 = Bt + (size_t)(tileN + srow + 64) * K + scol;
    u16* lA0 = &sA[0][0] + w * 512;
    u16* lA1 = &sA[0][0] + 2048 + w * 512;
    u16* lB0 = &sB[0][0] + w * 512;
    u16* lB1 = &sB[0][0] + 2048 + w * 512;

    int aoff[4], boff[4];
#pragma unroll
    for (int m = 0; m < 4; m++) aoff[m] = (wr * 64 + m * 16 + l16) * 32 + lq * 8;
#pragma unroll
    for (int n = 0; n < 4; n++) boff[n] = (wc * 64 + n * 16 + l16) * 32 + lq * 8;

    const int nk = K >> 5;
    gload16(gA0, lA0);
    gload16(gA1, lA1);
    gload16(gB0, lB0);
    gload16(gB1, lB1);
    __syncthreads();
    int cur = 0;
    for (int kk = 0; kk < nk; ++kk) {
        if (kk + 1 < nk) {
            int nb = (cur ^ 1) * 4096;
            const u16* a0 = gA0 + (size_t)(kk + 1) * 32;
            const u16* a1 = gA1 + (size_t)(kk + 1) * 32;
            const u16* b0 = gB0 + (size_t)(kk + 1) * 32;
            const u16* b1 = gB1 + (size_t)(kk + 1) * 32;
            gload16(a0, lA0 + nb);
            gload16(a1, lA1 + nb);
            gload16(b0, lB0 + nb);
            gload16(b1, lB1 + nb);
        }
        const u16* bA = &sA[0][0] + cur * 4096;
        const u16* bB = &sB[0][0] + cur * 4096;
        bf16x8 af[4], bfr[4];
#pragma unroll
        for (int m = 0; m < 4; m++) af[m] = *(const bf16x8*)&bA[aoff[m]];
#pragma unroll
        for (int n = 0; n < 4; n++) bfr[n] = *(const bf16x8*)&bB[boff[n]];
        __builtin_amdgcn_s_setprio(1);
#pragma unroll
        for (int m = 0; m < 4; m++)
#pragma unroll
            for (int n = 0; n < 4; n++)
                acc[m][n] = __builtin_amdgcn_mfma_f32_16x16x32_bf16(af[m], bfr[n], acc[m][n], 0, 0, 0);
        __builtin_amdgcn_s_setprio(0);
        __syncthreads();
        cur ^= 1;
    }

    const bool isrope = (tileN >= 1536);
#pragma unroll
    for (int n = 0; n < 4; n++) {
        int col = tileN + wc * 64 + n * 16 + l16;
        float bv = bcat[col];
#pragma unroll
        for (int m = 0; m < 4; m++) {
            int rowb = tileM + wr * 64 + m * 16 + (lq << 2);
#pragma unroll
            for (int r = 0; r < 4; r++) {
                float v = acc[m][n][r] + bv;
                if (!isrope) dcat[(size_t)(rowb + r) * 1536 + col] = v;
                else         krbuf[(size_t)(rowb + r) * 1024 + (col - 1536)] = f2bf(v);
            }
        }
    }
}

// ---------------- RMS norm (row-wise, strided in), fp32 in -> bf16 out --------
template <int C>
__global__ __launch_bounds__(256) void rmsnorm_bf16(
    const float* __restrict__ in, int istride, const float* __restrict__ wgt, u16* __restrict__ out)
{
    const int row = blockIdx.x;
    const int tid = threadIdx.x;
    constexpr int PER = C / 256;
    const float* p = in + (size_t)row * istride;
    float v[PER];
    float ss = 0.f;
#pragma unroll
    for (int i = 0; i < PER; i++) { v[i] = p[tid + i * 256]; ss += v[i] * v[i]; }
#pragma unroll
    for (int o = 32; o; o >>= 1) ss += __shfl_xor(ss, o, 64);
    __shared__ float red[4];
    if ((tid & 63) == 0) red[tid >> 6] = ss;
    __syncthreads();
    float tot = red[0] + red[1] + red[2] + red[3];
    float inv = rsqrtf(tot / (float)C + RMS_EPS);
    u16* q = out + (size_t)row * C;
#pragma unroll
    for (int i = 0; i < PER; i++) {
        int c = tid + i * 256;
        q[c] = f2bf(v[i] * inv * wgt[c]);
    }
}

// ---------------- V transpose: kvbuf[token][h*192+64+d] -> vT[(h*128+d)*4096+token]
__global__ __launch_bounds__(256) void transpose_v(
    const u16* __restrict__ kvbuf, u16* __restrict__ vT)
{
    __shared__ alignas(16) u16 tile[64][72];
    const int tid = threadIdx.x;
    const int t0 = blockIdx.x * 64;
    const int h = blockIdx.y >> 1, dh = blockIdx.y & 1;
    const int trow = tid >> 2, c8 = (tid & 3) * 8;
    const u16* src = kvbuf + (size_t)(t0 + trow) * 3072 + h * 192 + 64 + dh * 64 + c8;
    *(bf16x8*)&tile[trow][c8]      = *(const bf16x8*)src;
    *(bf16x8*)&tile[trow][c8 + 32] = *(const bf16x8*)(src + 32);
    __syncthreads();
    const int drow = tid >> 2, tc8 = (tid & 3) * 8;
    bf16x8 a, b2;
#pragma unroll
    for (int j = 0; j < 8; j++) {
        a[j]  = (short)tile[tc8 + j][drow];
        b2[j] = (short)tile[tc8 + 32 + j][drow];
    }
    u16* dst = vT + (size_t)(h * 128 + dh * 64 + drow) * MROWS + t0 + tc8;
    *(bf16x8*)dst = a;
    *(bf16x8*)(dst + 32) = b2;
}

// ---------------- causal flash attention: in-block K-split, 8 waves ----------
// Block = (bh, qt), 512 threads, __launch_bounds__(512,2) -> VGPR cap 256 (NO
// spill; round 12's failure was the (512,4) clamp to 64 VGPR + scratch traffic).
// Waves 0-3 (group A) process k-tiles [0, qt+1); waves 4-7 (group B) process
// [qt+1, 2qt+2). Both groups run EXACTLY qt+1 iterations -> aligned barriers.
// Critical path halves vs round 8 (16 iters max, was 32). qt = 15 - y puts
// longest blocks first for greedy backfill (512 blocks, ~1 block/CU).
// End: B passes (m,l,O) via LDS; A rescale-merges and writes.
__global__ __launch_bounds__(512, 2) void mla_attn(
    const u16* __restrict__ qbuf,   // (4096, 2048) head-major h*128
    const u16* __restrict__ kvbuf,  // (4096, 3072) per head 192: knope(64) v(128)
    const u16* __restrict__ krbuf,  // (4096, 1024) per head 64
    const u16* __restrict__ vT,     // (h*128+d, 4096 tokens)
    u16* __restrict__ obuf)         // (4096, 2048)
{
    const int bh = blockIdx.x;
    const int qt = 15 - blockIdx.y;   // longest blocks dispatch first
    const int b = bh >> 4, hh = bh & 15;
    const int tid = threadIdx.x, lane = tid & 63;
    const int w8 = tid >> 6;
    const int grp = w8 >> 2;        // 0 = A (low k half), 1 = B (high k half)
    const int w = w8 & 3;           // wave-in-group; q rows w*32..w*32+31
    const int l31 = lane & 31, hx = lane >> 5;
    const int tg = tid & 255;       // thread-in-group

    __shared__ alignas(16) char smem[68608];
    char* sK  = smem + grp * 16384;            // [64][128] bf16, XOR-swizzled
    char* sVt = smem + 32768 + grp * 16384;    // [128][64] bf16, XOR-swizzled
    float* mO  = (float*)smem;                 // merge: [4 waves][32 q][132] f32
    float* mml = (float*)(smem + 67584);       // merge: [4 waves][32 q][2] f32

    const int rowbase = b * Ss;
    const int q0 = qt * 128;
    const int niter = qt + 1;
    const int kbase = grp ? niter : 0;

    const int sr = tg >> 2, sc = (tg & 3) * 32;   // K staging (group-local)
    const int vd = tg >> 1, vh = (tg & 1) * 32;   // V staging (group-local)
    const float C1 = 0.12751742f;    // softmax_scale * log2(e)
    const float THRR = 90.5f;        // defer-max threshold (raw score units)

    // Q fragments: lane (q=l31, hx) needs d-chunks (2c + hx), c = 0..7
    bf16x8 qf[8];
    {
        const u16* qp = qbuf + (size_t)(rowbase + q0 + w * 32 + l31) * 2048 + hh * 128;
#pragma unroll
        for (int c = 0; c < 8; c++) qf[c] = *(const bf16x8*)(qp + (2 * c + hx) * 8);
    }
    float mi = -3e38f, li = 0.f;
    f32x16 o[4];
#pragma unroll
    for (int d = 0; d < 4; d++)
#pragma unroll
        for (int i = 0; i < 16; i++) o[d][i] = 0.f;

    bf16x8 kr[4], vr[4];
    {   // prologue: tile kbase -> regs
        const int krow = rowbase + kbase * 64 + sr;
        const u16* src = (sc < 64)
            ? kvbuf + (size_t)krow * 3072 + hh * 192 + sc
            : krbuf + (size_t)krow * 1024 + hh * 64 + (sc - 64);
#pragma unroll
        for (int j = 0; j < 4; j++) kr[j] = *(const bf16x8*)(src + j * 8);
        const u16* vsrc = vT + (size_t)(hh * 128 + vd) * MROWS + rowbase + kbase * 64 + vh;
#pragma unroll
        for (int j = 0; j < 4; j++) vr[j] = *(const bf16x8*)(vsrc + j * 8);
    }

#pragma unroll 1
    for (int t = 0; t < niter; ++t) {
        const int kt = kbase + t;
        __syncthreads();
#pragma unroll
        for (int j = 0; j < 4; j++) {
            int byteoff = sr * 256 + (sc + j * 8) * 2;
            *(bf16x8*)(sK + (byteoff ^ ((sr & 7) << 4))) = kr[j];
        }
#pragma unroll
        for (int j = 0; j < 4; j++) {
            int byteoff = vd * 128 + (vh + j * 8) * 2;
            *(bf16x8*)(sVt + (byteoff ^ ((vd & 7) << 4))) = vr[j];
        }
        __syncthreads();
        if (t + 1 < niter) {   // prefetch next tile into regs (hides under compute)
            const int krow = rowbase + (kt + 1) * 64 + sr;
            const u16* src = (sc < 64)
                ? kvbuf + (size_t)krow * 3072 + hh * 192 + sc
                : krbuf + (size_t)krow * 1024 + hh * 64 + (sc - 64);
#pragma unroll
            for (int j = 0; j < 4; j++) kr[j] = *(const bf16x8*)(src + j * 8);
            const u16* vsrc = vT + (size_t)(hh * 128 + vd) * MROWS + rowbase + (kt + 1) * 64 + vh;
#pragma unroll
            for (int j = 0; j < 4; j++) vr[j] = *(const bf16x8*)(vsrc + j * 8);
        }

        // wave-dead skip: this wave's q range is [q0+32w, q0+32w+31]
        const bool alive = (kt * 64) <= (q0 + w * 32 + 31);
        if (alive) {
            // QK^T swapped: A=K(32k x 16d), B=Q(16d x 32q) -> D[k][q], q=l31
            f32x16 scf[2];
#pragma unroll
            for (int b2 = 0; b2 < 2; b2++)
#pragma unroll
                for (int i = 0; i < 16; i++) scf[b2][i] = 0.f;
            __builtin_amdgcn_s_setprio(1);
#pragma unroll
            for (int s = 0; s < 8; s++) {
#pragma unroll
                for (int b2 = 0; b2 < 2; b2++) {
                    int krow = b2 * 32 + l31;
                    int kbyte = (krow * 256 + s * 32 + hx * 16) ^ ((l31 & 7) << 4);
                    bf16x8 kf = *(const bf16x8*)(sK + kbyte);
                    scf[b2] = __builtin_amdgcn_mfma_f32_32x32x16_bf16(kf, qf[s], scf[b2], 0, 0, 0);
                }
            }
            __builtin_amdgcn_s_setprio(0);

            // causal mask (only diagonal-adjacent tiles for this wave)
            if (kt * 64 + 63 > q0 + w * 32) {
                const int qg = q0 + w * 32 + l31;
#pragma unroll
                for (int b2 = 0; b2 < 2; b2++)
#pragma unroll
                    for (int rg = 0; rg < 16; rg++) {
                        int kg = kt * 64 + b2 * 32 + (rg & 3) + 8 * (rg >> 2) + 4 * hx;
                        if (kg > qg) scf[b2][rg] = -3e38f;
                    }
            }
            // online softmax: in-lane over 32 vals + partner exchange
            float mx = mi;
#pragma unroll
            for (int b2 = 0; b2 < 2; b2++)
#pragma unroll
                for (int rg = 0; rg < 16; rg++) mx = fmaxf(mx, scf[b2][rg]);
            mx = fmaxf(mx, __shfl_xor(mx, 32, 64));
            if (!__all(mx - mi <= THRR)) {   // T13 defer-max
                float f = exp2_fast((mi - mx) * C1);
                li *= f;
#pragma unroll
                for (int d = 0; d < 4; d++)
#pragma unroll
                    for (int i = 0; i < 16; i++) o[d][i] *= f;
                mi = mx;
            }
            float mc = mi * C1;
            float rs = 0.f;
#pragma unroll
            for (int b2 = 0; b2 < 2; b2++)
#pragma unroll
                for (int rg = 0; rg < 16; rg++) {
                    float pv = exp2_fast(__fmaf_rn(scf[b2][rg], C1, -mc));
                    scf[b2][rg] = pv;
                    rs += pv;
                }
            rs += __shfl_xor(rs, 32, 64);
            li += rs;

            // pack P -> bf16 pairs: pk[b][g] covers rows {8g..8g+3} + 4*hx
            u32 pk[2][4][2];
#pragma unroll
            for (int b2 = 0; b2 < 2; b2++)
#pragma unroll
                for (int g = 0; g < 4; g++) {
                    pk[b2][g][0] = (u32)f2bf(scf[b2][4 * g + 0]) | ((u32)f2bf(scf[b2][4 * g + 1]) << 16);
                    pk[b2][g][1] = (u32)f2bf(scf[b2][4 * g + 2]) | ((u32)f2bf(scf[b2][4 * g + 3]) << 16);
                }

            // PV swapped: A=V^T(32d x 16k), B=P^T(16k x 32q) -> O^T[d][q]
            __builtin_amdgcn_s_setprio(1);
#pragma unroll
            for (int t4 = 0; t4 < 4; t4++) {
                const int b2 = t4 >> 1, s = t4 & 1;
                // exchange with partner (lane^32): send the group partner needs
                u32 send0 = hx ? pk[b2][2 * s][0] : pk[b2][2 * s + 1][0];
                u32 send1 = hx ? pk[b2][2 * s][1] : pk[b2][2 * s + 1][1];
                u32 r0 = (u32)__shfl_xor((int)send0, 32, 64);
                u32 r1 = (u32)__shfl_xor((int)send1, 32, 64);
                union { u32 wd[4]; bf16x8 v; } pu;
                pu.wd[0] = hx ? r0 : pk[b2][2 * s][0];
                pu.wd[1] = hx ? r1 : pk[b2][2 * s][1];
                pu.wd[2] = hx ? pk[b2][2 * s + 1][0] : r0;
                pu.wd[3] = hx ? pk[b2][2 * s + 1][1] : r1;
#pragma unroll
                for (int dblk = 0; dblk < 4; dblk++) {
                    int vrow = dblk * 32 + l31;
                    int vbyte = (vrow * 128 + t4 * 32 + hx * 16) ^ ((l31 & 7) << 4);
                    bf16x8 vf = *(const bf16x8*)(sVt + vbyte);
                    o[dblk] = __builtin_amdgcn_mfma_f32_32x32x16_bf16(vf, pu.v, o[dblk], 0, 0, 0);
                }
            }
            __builtin_amdgcn_s_setprio(0);
        }
    }

    // ---- merge: group B publishes (m, l, O) via LDS; group A combines ----
    __syncthreads();   // all staging reads done; safe to overlay merge buffers
    if (grp) {
#pragma unroll
        for (int dblk = 0; dblk < 4; dblk++)
#pragma unroll
            for (int rg = 0; rg < 4; rg++) {
                int d0 = dblk * 32 + rg * 8 + hx * 4;
                f32x4 v;
                v[0] = o[dblk][rg * 4 + 0]; v[1] = o[dblk][rg * 4 + 1];
                v[2] = o[dblk][rg * 4 + 2]; v[3] = o[dblk][rg * 4 + 3];
                *(f32x4*)&mO[(w * 32 + l31) * 132 + d0] = v;
            }
        if (hx == 0) {
            mml[(w * 32 + l31) * 2 + 0] = mi;
            mml[(w * 32 + l31) * 2 + 1] = li;
        }
    }
    __syncthreads();
    if (!grp) {
        float mB = mml[(w * 32 + l31) * 2 + 0];
        float lB = mml[(w * 32 + l31) * 2 + 1];
        float m = fmaxf(mi, mB);
        float a0 = exp2_fast((mi - m) * C1);
        float a1 = exp2_fast((mB - m) * C1);
        float linv = 1.f / (li * a0 + lB * a1);
        u16* op = obuf + (size_t)(rowbase + q0 + w * 32 + l31) * 2048 + hh * 128;
#pragma unroll
        for (int dblk = 0; dblk < 4; dblk++)
#pragma unroll
            for (int rg = 0; rg < 4; rg++) {
                int d0 = dblk * 32 + rg * 8 + hx * 4;
                f32x4 ob = *(const f32x4*)&mO[(w * 32 + l31) * 132 + d0];
                ushort4 ov;
                ov.x = f2bf((o[dblk][rg * 4 + 0] * a0 + ob[0] * a1) * linv);
                ov.y = f2bf((o[dblk][rg * 4 + 1] * a0 + ob[1] * a1) * linv);
                ov.z = f2bf((o[dblk][rg * 4 + 2] * a0 + ob[2] * a1) * linv);
                ov.w = f2bf((o[dblk][rg * 4 + 3] * a0 + ob[3] * a1) * linv);
                *(ushort4*)(op + d0) = ov;
            }
    }
}

// ---------------- launch ----------------
extern "C" void kernel_launch(void* const* d_in, const int* in_sizes, int n_in,
                              void* d_out, int out_size, void* d_ws, size_t ws_size,
                              hipStream_t stream) {
    const float* x        = (const float*)d_in[0];
    const float* q_down_w = (const float*)d_in[1];
    const float* q_down_b = (const float*)d_in[2];
    const float* q_norm_w = (const float*)d_in[3];
    const float* q_up_w   = (const float*)d_in[4];
    const float* q_up_b   = (const float*)d_in[5];
    const float* kv_down_w= (const float*)d_in[6];
    const float* kv_down_b= (const float*)d_in[7];
    const float* kv_norm_w= (const float*)d_in[8];
    const float* kv_up_w  = (const float*)d_in[9];
    const float* kv_up_b  = (const float*)d_in[10];
    const float* k_rope_w = (const float*)d_in[11];
    const float* k_rope_b = (const float*)d_in[12];
    const float* out_w    = (const float*)d_in[13];
    const float* out_b    = (const float*)d_in[14];

    char* ws = (char*)d_ws;
    u16* xbf    = (u16*)(ws + 0);          // 16.78 MB ; later reused as vT
    u16* wcat   = (u16*)(ws + 16777216);   // 10.49 MB (2560x2048 bf16)
    u16* quw    = (u16*)(ws + 27262976);   // 4.19 MB
    u16* kvuw   = (u16*)(ws + 31457280);   // 3.15 MB
    u16* outw   = (u16*)(ws + 34603008);   // 8.39 MB
    float* bcat = (float*)(ws + 42991616); // 10 KB (pad to 16 KB)
    float* dcat = (float*)(ws + 43008000); // 25.17 MB (4096x1536 f32); reused as attnbuf
    u16* cq     = (u16*)(ws + 68173824);   // 8.39 MB
    u16* ckv    = (u16*)(ws + 76562432);   // 4.19 MB
    u16* qbuf   = (u16*)(ws + 80756736);   // 16.78 MB
    u16* kvbuf  = (u16*)(ws + 97533952);   // 25.17 MB
    u16* krbuf  = (u16*)(ws + 122699776);  // 8.39 MB  (end 131,088,384)
    u16* vT     = (u16*)(ws + 0);          // alias xbf (dead after gemm_down)
    u16* attnbuf= (u16*)(ws + 43008000);   // alias dcat (dead after rmsnorms)

    cvt_all<<<20992, 256, 0, stream>>>(
        x, xbf,
        q_down_w,  wcat,
        kv_down_w, wcat + 1024 * 2048,
        k_rope_w,  wcat + 1536 * 2048,
        q_up_w,    quw,
        kv_up_w,   kvuw,
        out_w,     outw);
    build_bcat<<<10, 256, 0, stream>>>(q_down_b, kv_down_b, k_rope_b, bcat);

    // fused down projections: x @ [q_down|kv_down|k_rope]^T
    gemm_down<<<dim3(20, 32), 256, 0, stream>>>(xbf, wcat, bcat, dcat, krbuf);
    rmsnorm_bf16<1024><<<MROWS, 256, 0, stream>>>(dcat, 1536, q_norm_w, cq);
    rmsnorm_bf16<512><<<MROWS, 256, 0, stream>>>(dcat + 1024, 1536, kv_norm_w, ckv);
    // up projections
    gemm_bt<u16><<<dim3(16, 32), 256, 0, stream>>>(cq, quw, q_up_b, qbuf, MROWS, 2048, 1024);
    gemm_bt<u16><<<dim3(24, 32), 256, 0, stream>>>(ckv, kvuw, kv_up_b, kvbuf, MROWS, 3072, 512);
    // V transpose (vT aliases xbf; xbf dead after gemm_down)
    transpose_v<<<dim3(64, 32), 256, 0, stream>>>(kvbuf, vT);
    // attention: 512 blocks x 512 threads, in-block K-split, longest-first
    mla_attn<<<dim3(32, 16), 512, 0, stream>>>(qbuf, kvbuf, krbuf, vT, attnbuf);
    // output projection
    gemm_bt<float><<<dim3(16, 32), 256, 0, stream>>>(attnbuf, outw, out_b, (float*)d_out, MROWS, 2048, 2048);
}

// Round 15
// 258.151 us; speedup vs baseline: 1.7328x; 1.0070x over previous
//
#include <hip/hip_runtime.h>
#include <hip/hip_bf16.h>

typedef __attribute__((ext_vector_type(8))) short bf16x8;
typedef __attribute__((ext_vector_type(4))) float f32x4;
typedef __attribute__((ext_vector_type(16))) float f32x16;
typedef unsigned short u16;
typedef unsigned int u32;

#define RMS_EPS 1.1920929e-07f

constexpr int Bb = 2, Ss = 2048, DM = 2048, NH = 16;
constexpr int MROWS = Bb * Ss; // 4096

__device__ __forceinline__ u16 f2bf(float f) {
    __hip_bfloat16 h = __float2bfloat16(f);
    return *reinterpret_cast<u16*>(&h);
}

__device__ __forceinline__ float exp2_fast(float x) {
    float r; asm("v_exp_f32 %0, %1" : "=v"(r) : "v"(x)); return r;
}

__device__ __forceinline__ void gload16(const void* g, void* l) {
    __builtin_amdgcn_global_load_lds(
        (const __attribute__((address_space(1))) unsigned int*)g,
        (__attribute__((address_space(3))) unsigned int*)l, 16, 0, 0);
}

// ---------------- merged fp32 -> bf16 convert (7 segments, sizes fixed) -------
__global__ __launch_bounds__(256) void cvt_all(
    const float* __restrict__ s0, u16* __restrict__ d0,
    const float* __restrict__ s1, u16* __restrict__ d1,
    const float* __restrict__ s2, u16* __restrict__ d2,
    const float* __restrict__ s3, u16* __restrict__ d3,
    const float* __restrict__ s4, u16* __restrict__ d4,
    const float* __restrict__ s5, u16* __restrict__ d5,
    const float* __restrict__ s6, u16* __restrict__ d6)
{
    int i = blockIdx.x * 256 + threadIdx.x;   // float4 index; grid covers exactly 5373952
    const float* s; u16* d; int off;
    if (i < 2097152)      { s = s0; d = d0; off = 0; }
    else if (i < 2621440) { s = s1; d = d1; off = 2097152; }
    else if (i < 2883584) { s = s2; d = d2; off = 2621440; }
    else if (i < 3407872) { s = s3; d = d3; off = 2883584; }
    else if (i < 3932160) { s = s4; d = d4; off = 3407872; }
    else if (i < 4325376) { s = s5; d = d5; off = 3932160; }
    else                  { s = s6; d = d6; off = 4325376; }
    int j = i - off;
    float4 v = reinterpret_cast<const float4*>(s)[j];
    ushort4 o;
    o.x = f2bf(v.x); o.y = f2bf(v.y); o.z = f2bf(v.z); o.w = f2bf(v.w);
    reinterpret_cast<ushort4*>(d)[j] = o;
}

__global__ void build_bcat(const float* __restrict__ qb, const float* __restrict__ kvb,
                           const float* __restrict__ krb, float* __restrict__ bcat) {
    int i = blockIdx.x * 256 + threadIdx.x;
    if (i < 1024) bcat[i] = qb[i];
    else if (i < 1536) bcat[i] = kvb[i - 1024];
    else if (i < 2560) bcat[i] = krb[i - 1536];
}

// XCD-chunked bijective block remap (T1). Requires nwg % 8 == 0.
__device__ __forceinline__ void xcd_remap(int& bx, int& by) {
    int nx = gridDim.x, ny = gridDim.y;
    int nwg = nx * ny;
    if ((nwg & 7) != 0) return;
    int flat = blockIdx.x + nx * blockIdx.y;
    int chunk = nwg >> 3;
    int wg = (flat & 7) * chunk + (flat >> 3);
    by = wg % ny;          // M-tile fastest within an XCD chunk
    bx = wg / ny;          // few N-columns per XCD -> B-panel L2 reuse
}

// ---------------- GEMM: C(M,N) = A(M,K) * Bt(N,K)^T + bias ----------------
// 2-phase double-buffered: STAGE(t+1) issued BEFORE compute(t); 1 barrier/K-step.
template <typename OutT>
__global__ __launch_bounds__(256) void gemm_bt(
    const u16* __restrict__ A, const u16* __restrict__ Bt,
    const float* __restrict__ bias, OutT* __restrict__ C,
    int M, int N, int K)
{
    __shared__ alignas(16) u16 sA[2][128 * 32];
    __shared__ alignas(16) u16 sB[2][128 * 32];
    const int tid = threadIdx.x;
    const int lane = tid & 63;
    const int w = tid >> 6;
    const int wr = w >> 1, wc = w & 1;
    const int l16 = lane & 15, lq = lane >> 4;
    int bx = blockIdx.x, by = blockIdx.y;
    xcd_remap(bx, by);
    const int tileM = by * 128;
    const int tileN = bx * 128;

    f32x4 acc[4][4];
#pragma unroll
    for (int m = 0; m < 4; m++)
#pragma unroll
        for (int n = 0; n < 4; n++)
#pragma unroll
            for (int r = 0; r < 4; r++) acc[m][n][r] = 0.f;

    const int srow = w * 16 + (lane >> 2);
    const int scol = (lane & 3) * 8;
    const u16* gA0 = A + (size_t)(tileM + srow) * K + scol;
    const u16* gA1 = A + (size_t)(tileM + srow + 64) * K + scol;
    const u16* gB0 = Bt + (size_t)(tileN + srow) * K + scol;
    const u16* gB1 = Bt + (size_t)(tileN + srow + 64) * K + scol;
    u16* lA0 = &sA[0][0] + w * 512;
    u16* lA1 = &sA[0][0] + 2048 + w * 512;
    u16* lB0 = &sB[0][0] + w * 512;
    u16* lB1 = &sB[0][0] + 2048 + w * 512;

    int aoff[4], boff[4];
#pragma unroll
    for (int m = 0; m < 4; m++) aoff[m] = (wr * 64 + m * 16 + l16) * 32 + lq * 8;
#pragma unroll
    for (int n = 0; n < 4; n++) boff[n] = (wc * 64 + n * 16 + l16) * 32 + lq * 8;

    const int nk = K >> 5;
    // prologue: stage tile 0 into buffer 0
    gload16(gA0, lA0);
    gload16(gA1, lA1);
    gload16(gB0, lB0);
    gload16(gB1, lB1);
    __syncthreads();
    int cur = 0;
    for (int kk = 0; kk < nk; ++kk) {
        if (kk + 1 < nk) {   // issue next-tile DMA into other buffer (overlaps compute)
            int nb = (cur ^ 1) * 4096;
            const u16* a0 = gA0 + (size_t)(kk + 1) * 32;
            const u16* a1 = gA1 + (size_t)(kk + 1) * 32;
            const u16* b0 = gB0 + (size_t)(kk + 1) * 32;
            const u16* b1 = gB1 + (size_t)(kk + 1) * 32;
            gload16(a0, lA0 + nb);
            gload16(a1, lA1 + nb);
            gload16(b0, lB0 + nb);
            gload16(b1, lB1 + nb);
        }
        const u16* bA = &sA[0][0] + cur * 4096;
        const u16* bB = &sB[0][0] + cur * 4096;
        bf16x8 af[4], bfr[4];
#pragma unroll
        for (int m = 0; m < 4; m++) af[m] = *(const bf16x8*)&bA[aoff[m]];
#pragma unroll
        for (int n = 0; n < 4; n++) bfr[n] = *(const bf16x8*)&bB[boff[n]];
        __builtin_amdgcn_s_setprio(1);
#pragma unroll
        for (int m = 0; m < 4; m++)
#pragma unroll
            for (int n = 0; n < 4; n++)
                acc[m][n] = __builtin_amdgcn_mfma_f32_16x16x32_bf16(af[m], bfr[n], acc[m][n], 0, 0, 0);
        __builtin_amdgcn_s_setprio(0);
        __syncthreads();   // drains staged DMA (had full compute phase to land) + read-done
        cur ^= 1;
    }

#pragma unroll
    for (int n = 0; n < 4; n++) {
        int col = tileN + wc * 64 + n * 16 + l16;
        float bv = bias ? bias[col] : 0.f;
#pragma unroll
        for (int m = 0; m < 4; m++) {
            int rowb = tileM + wr * 64 + m * 16 + (lq << 2);
#pragma unroll
            for (int r = 0; r < 4; r++) {
                float v = acc[m][n][r] + bv;
                if constexpr (sizeof(OutT) == 2)
                    C[(size_t)(rowb + r) * N + col] = (OutT)f2bf(v);
                else
                    C[(size_t)(rowb + r) * N + col] = (OutT)v;
            }
        }
    }
}

// ---------------- fused down-proj GEMM: N=2560 (1024 q | 512 kv | 1024 rope) ----
// Same 2-phase schedule as gemm_bt.
__global__ __launch_bounds__(256) void gemm_down(
    const u16* __restrict__ A, const u16* __restrict__ Bt,
    const float* __restrict__ bcat, float* __restrict__ dcat,
    u16* __restrict__ krbuf)
{
    constexpr int K = 2048;
    __shared__ alignas(16) u16 sA[2][128 * 32];
    __shared__ alignas(16) u16 sB[2][128 * 32];
    const int tid = threadIdx.x;
    const int lane = tid & 63;
    const int w = tid >> 6;
    const int wr = w >> 1, wc = w & 1;
    const int l16 = lane & 15, lq = lane >> 4;
    int bx = blockIdx.x, by = blockIdx.y;
    xcd_remap(bx, by);
    const int tileM = by * 128;
    const int tileN = bx * 128;

    f32x4 acc[4][4];
#pragma unroll
    for (int m = 0; m < 4; m++)
#pragma unroll
        for (int n = 0; n < 4; n++)
#pragma unroll
            for (int r = 0; r < 4; r++) acc[m][n][r] = 0.f;

    const int srow = w * 16 + (lane >> 2);
    const int scol = (lane & 3) * 8;
    const u16* gA0 = A + (size_t)(tileM + srow) * K + scol;
    const u16* gA1 = A + (size_t)(tileM + srow + 64) * K + scol;
    const u16* gB0 = Bt + (size_t)(tileN + srow) * K + scol;
    const u16* gB1 = Bt + (size_t)(tileN + srow + 64) * K + scol;
    u16* lA0 = &sA[0][0] + w * 512;
    u16* lA1 = &sA[0][0] + 2048 + w * 512;
    u16* lB0 = &sB[0][0] + w * 512;
    u16* lB1 = &sB[0][0] + 2048 + w * 512;

    int aoff[4], boff[4];
#pragma unroll
    for (int m = 0; m < 4; m++) aoff[m] = (wr * 64 + m * 16 + l16) * 32 + lq * 8;
#pragma unroll
    for (int n = 0; n < 4; n++) boff[n] = (wc * 64 + n * 16 + l16) * 32 + lq * 8;

    const int nk = K >> 5;
    gload16(gA0, lA0);
    gload16(gA1, lA1);
    gload16(gB0, lB0);
    gload16(gB1, lB1);
    __syncthreads();
    int cur = 0;
    for (int kk = 0; kk < nk; ++kk) {
        if (kk + 1 < nk) {
            int nb = (cur ^ 1) * 4096;
            const u16* a0 = gA0 + (size_t)(kk + 1) * 32;
            const u16* a1 = gA1 + (size_t)(kk + 1) * 32;
            const u16* b0 = gB0 + (size_t)(kk + 1) * 32;
            const u16* b1 = gB1 + (size_t)(kk + 1) * 32;
            gload16(a0, lA0 + nb);
            gload16(a1, lA1 + nb);
            gload16(b0, lB0 + nb);
            gload16(b1, lB1 + nb);
        }
        const u16* bA = &sA[0][0] + cur * 4096;
        const u16* bB = &sB[0][0] + cur * 4096;
        bf16x8 af[4], bfr[4];
#pragma unroll
        for (int m = 0; m < 4; m++) af[m] = *(const bf16x8*)&bA[aoff[m]];
#pragma unroll
        for (int n = 0; n < 4; n++) bfr[n] = *(const bf16x8*)&bB[boff[n]];
        __builtin_amdgcn_s_setprio(1);
#pragma unroll
        for (int m = 0; m < 4; m++)
#pragma unroll
            for (int n = 0; n < 4; n++)
                acc[m][n] = __builtin_amdgcn_mfma_f32_16x16x32_bf16(af[m], bfr[n], acc[m][n], 0, 0, 0);
        __builtin_amdgcn_s_setprio(0);
        __syncthreads();
        cur ^= 1;
    }

    const bool isrope = (tileN >= 1536);
#pragma unroll
    for (int n = 0; n < 4; n++) {
        int col = tileN + wc * 64 + n * 16 + l16;
        float bv = bcat[col];
#pragma unroll
        for (int m = 0; m < 4; m++) {
            int rowb = tileM + wr * 64 + m * 16 + (lq << 2);
#pragma unroll
            for (int r = 0; r < 4; r++) {
                float v = acc[m][n][r] + bv;
                if (!isrope) dcat[(size_t)(rowb + r) * 1536 + col] = v;
                else         krbuf[(size_t)(rowb + r) * 1024 + (col - 1536)] = f2bf(v);
            }
        }
    }
}

// ---------------- RMS norm (row-wise, strided in), fp32 in -> bf16 out --------
template <int C>
__global__ __launch_bounds__(256) void rmsnorm_bf16(
    const float* __restrict__ in, int istride, const float* __restrict__ wgt, u16* __restrict__ out)
{
    const int row = blockIdx.x;
    const int tid = threadIdx.x;
    constexpr int PER = C / 256;
    const float* p = in + (size_t)row * istride;
    float v[PER];
    float ss = 0.f;
#pragma unroll
    for (int i = 0; i < PER; i++) { v[i] = p[tid + i * 256]; ss += v[i] * v[i]; }
#pragma unroll
    for (int o = 32; o; o >>= 1) ss += __shfl_xor(ss, o, 64);
    __shared__ float red[4];
    if ((tid & 63) == 0) red[tid >> 6] = ss;
    __syncthreads();
    float tot = red[0] + red[1] + red[2] + red[3];
    float inv = rsqrtf(tot / (float)C + RMS_EPS);
    u16* q = out + (size_t)row * C;
#pragma unroll
    for (int i = 0; i < PER; i++) {
        int c = tid + i * 256;
        q[c] = f2bf(v[i] * inv * wgt[c]);
    }
}

// ---------------- V transpose: kvbuf[token][h*192+64+d] -> vT[(h*128+d)*4096+token]
__global__ __launch_bounds__(256) void transpose_v(
    const u16* __restrict__ kvbuf, u16* __restrict__ vT)
{
    __shared__ alignas(16) u16 tile[64][72];
    const int tid = threadIdx.x;
    const int t0 = blockIdx.x * 64;
    const int h = blockIdx.y >> 1, dh = blockIdx.y & 1;
    const int trow = tid >> 2, c8 = (tid & 3) * 8;
    const u16* src = kvbuf + (size_t)(t0 + trow) * 3072 + h * 192 + 64 + dh * 64 + c8;
    *(bf16x8*)&tile[trow][c8]      = *(const bf16x8*)src;
    *(bf16x8*)&tile[trow][c8 + 32] = *(const bf16x8*)(src + 32);
    __syncthreads();
    const int drow = tid >> 2, tc8 = (tid & 3) * 8;
    bf16x8 a, b2;
#pragma unroll
    for (int j = 0; j < 8; j++) {
        a[j]  = (short)tile[tc8 + j][drow];
        b2[j] = (short)tile[tc8 + 32 + j][drow];
    }
    u16* dst = vT + (size_t)(h * 128 + dh * 64 + drow) * MROWS + t0 + tc8;
    *(bf16x8*)dst = a;
    *(bf16x8*)(dst + 32) = b2;
}

// ---------------- causal flash attention: in-block K-split, 8 waves ----------
// Block = (bh, qt), 512 threads, __launch_bounds__(512,2). Waves 0-3 (group A)
// process k-tiles [0, qt+1); waves 4-7 (group B) process [qt+1, 2qt+2).
// LDS EXACTLY 64 KB (staging 4x16KB; merge overlays first 34.3KB in TWO passes)
// -> 2 blocks/CU co-resident (r14's 68.6KB allocation kept the 2nd block off
// the CU: occupancy 19.4% ~= 1 block). qt = 15 - y: longest blocks first.
__global__ __launch_bounds__(512, 2) void mla_attn(
    const u16* __restrict__ qbuf,   // (4096, 2048) head-major h*128
    const u16* __restrict__ kvbuf,  // (4096, 3072) per head 192: knope(64) v(128)
    const u16* __restrict__ krbuf,  // (4096, 1024) per head 64
    const u16* __restrict__ vT,     // (h*128+d, 4096 tokens)
    u16* __restrict__ obuf)         // (4096, 2048)
{
    const int bh = blockIdx.x;
    const int qt = 15 - blockIdx.y;   // longest blocks dispatch first
    const int b = bh >> 4, hh = bh & 15;
    const int tid = threadIdx.x, lane = tid & 63;
    const int w8 = tid >> 6;
    const int grp = w8 >> 2;        // 0 = A (low k half), 1 = B (high k half)
    const int w = w8 & 3;           // wave-in-group; q rows w*32..w*32+31
    const int l31 = lane & 31, hx = lane >> 5;
    const int tg = tid & 255;       // thread-in-group

    __shared__ alignas(16) char smem[65536];
    char* sK  = smem + grp * 16384;            // [64][128] bf16, XOR-swizzled
    char* sVt = smem + 32768 + grp * 16384;    // [128][64] bf16, XOR-swizzled
    float* mO  = (float*)smem;                 // merge (2 passes): [2 wv][32 q][132] f32
    float* mml = (float*)(smem + 33792);       // merge: [2 wv][32 q][2] f32

    const int rowbase = b * Ss;
    const int q0 = qt * 128;
    const int niter = qt + 1;
    const int kbase = grp ? niter : 0;

    const int sr = tg >> 2, sc = (tg & 3) * 32;   // K staging (group-local)
    const int vd = tg >> 1, vh = (tg & 1) * 32;   // V staging (group-local)
    const float C1 = 0.12751742f;    // softmax_scale * log2(e)
    const float THRR = 90.5f;        // defer-max threshold (raw score units)

    // Q fragments: lane (q=l31, hx) needs d-chunks (2c + hx), c = 0..7
    bf16x8 qf[8];
    {
        const u16* qp = qbuf + (size_t)(rowbase + q0 + w * 32 + l31) * 2048 + hh * 128;
#pragma unroll
        for (int c = 0; c < 8; c++) qf[c] = *(const bf16x8*)(qp + (2 * c + hx) * 8);
    }
    float mi = -3e38f, li = 0.f;
    f32x16 o[4];
#pragma unroll
    for (int d = 0; d < 4; d++)
#pragma unroll
        for (int i = 0; i < 16; i++) o[d][i] = 0.f;

    bf16x8 kr[4], vr[4];
    {   // prologue: tile kbase -> regs
        const int krow = rowbase + kbase * 64 + sr;
        const u16* src = (sc < 64)
            ? kvbuf + (size_t)krow * 3072 + hh * 192 + sc
            : krbuf + (size_t)krow * 1024 + hh * 64 + (sc - 64);
#pragma unroll
        for (int j = 0; j < 4; j++) kr[j] = *(const bf16x8*)(src + j * 8);
        const u16* vsrc = vT + (size_t)(hh * 128 + vd) * MROWS + rowbase + kbase * 64 + vh;
#pragma unroll
        for (int j = 0; j < 4; j++) vr[j] = *(const bf16x8*)(vsrc + j * 8);
    }

#pragma unroll 1
    for (int t = 0; t < niter; ++t) {
        const int kt = kbase + t;
        __syncthreads();
#pragma unroll
        for (int j = 0; j < 4; j++) {
            int byteoff = sr * 256 + (sc + j * 8) * 2;
            *(bf16x8*)(sK + (byteoff ^ ((sr & 7) << 4))) = kr[j];
        }
#pragma unroll
        for (int j = 0; j < 4; j++) {
            int byteoff = vd * 128 + (vh + j * 8) * 2;
            *(bf16x8*)(sVt + (byteoff ^ ((vd & 7) << 4))) = vr[j];
        }
        __syncthreads();
        if (t + 1 < niter) {   // prefetch next tile into regs (hides under compute)
            const int krow = rowbase + (kt + 1) * 64 + sr;
            const u16* src = (sc < 64)
                ? kvbuf + (size_t)krow * 3072 + hh * 192 + sc
                : krbuf + (size_t)krow * 1024 + hh * 64 + (sc - 64);
#pragma unroll
            for (int j = 0; j < 4; j++) kr[j] = *(const bf16x8*)(src + j * 8);
            const u16* vsrc = vT + (size_t)(hh * 128 + vd) * MROWS + rowbase + (kt + 1) * 64 + vh;
#pragma unroll
            for (int j = 0; j < 4; j++) vr[j] = *(const bf16x8*)(vsrc + j * 8);
        }

        // wave-dead skip: this wave's q range is [q0+32w, q0+32w+31]
        const bool alive = (kt * 64) <= (q0 + w * 32 + 31);
        if (alive) {
            // QK^T swapped: A=K(32k x 16d), B=Q(16d x 32q) -> D[k][q], q=l31
            f32x16 scf[2];
#pragma unroll
            for (int b2 = 0; b2 < 2; b2++)
#pragma unroll
                for (int i = 0; i < 16; i++) scf[b2][i] = 0.f;
            __builtin_amdgcn_s_setprio(1);
#pragma unroll
            for (int s = 0; s < 8; s++) {
#pragma unroll
                for (int b2 = 0; b2 < 2; b2++) {
                    int krow = b2 * 32 + l31;
                    int kbyte = (krow * 256 + s * 32 + hx * 16) ^ ((l31 & 7) << 4);
                    bf16x8 kf = *(const bf16x8*)(sK + kbyte);
                    scf[b2] = __builtin_amdgcn_mfma_f32_32x32x16_bf16(kf, qf[s], scf[b2], 0, 0, 0);
                }
            }
            __builtin_amdgcn_s_setprio(0);

            // causal mask (only diagonal-adjacent tiles for this wave)
            if (kt * 64 + 63 > q0 + w * 32) {
                const int qg = q0 + w * 32 + l31;
#pragma unroll
                for (int b2 = 0; b2 < 2; b2++)
#pragma unroll
                    for (int rg = 0; rg < 16; rg++) {
                        int kg = kt * 64 + b2 * 32 + (rg & 3) + 8 * (rg >> 2) + 4 * hx;
                        if (kg > qg) scf[b2][rg] = -3e38f;
                    }
            }
            // online softmax: in-lane over 32 vals + partner exchange
            float mx = mi;
#pragma unroll
            for (int b2 = 0; b2 < 2; b2++)
#pragma unroll
                for (int rg = 0; rg < 16; rg++) mx = fmaxf(mx, scf[b2][rg]);
            mx = fmaxf(mx, __shfl_xor(mx, 32, 64));
            if (!__all(mx - mi <= THRR)) {   // T13 defer-max
                float f = exp2_fast((mi - mx) * C1);
                li *= f;
#pragma unroll
                for (int d = 0; d < 4; d++)
#pragma unroll
                    for (int i = 0; i < 16; i++) o[d][i] *= f;
                mi = mx;
            }
            float mc = mi * C1;
            float rs = 0.f;
#pragma unroll
            for (int b2 = 0; b2 < 2; b2++)
#pragma unroll
                for (int rg = 0; rg < 16; rg++) {
                    float pv = exp2_fast(__fmaf_rn(scf[b2][rg], C1, -mc));
                    scf[b2][rg] = pv;
                    rs += pv;
                }
            rs += __shfl_xor(rs, 32, 64);
            li += rs;

            // pack P -> bf16 pairs: pk[b][g] covers rows {8g..8g+3} + 4*hx
            u32 pk[2][4][2];
#pragma unroll
            for (int b2 = 0; b2 < 2; b2++)
#pragma unroll
                for (int g = 0; g < 4; g++) {
                    pk[b2][g][0] = (u32)f2bf(scf[b2][4 * g + 0]) | ((u32)f2bf(scf[b2][4 * g + 1]) << 16);
                    pk[b2][g][1] = (u32)f2bf(scf[b2][4 * g + 2]) | ((u32)f2bf(scf[b2][4 * g + 3]) << 16);
                }

            // PV swapped: A=V^T(32d x 16k), B=P^T(16k x 32q) -> O^T[d][q]
            __builtin_amdgcn_s_setprio(1);
#pragma unroll
            for (int t4 = 0; t4 < 4; t4++) {
                const int b2 = t4 >> 1, s = t4 & 1;
                // exchange with partner (lane^32): send the group partner needs
                u32 send0 = hx ? pk[b2][2 * s][0] : pk[b2][2 * s + 1][0];
                u32 send1 = hx ? pk[b2][2 * s][1] : pk[b2][2 * s + 1][1];
                u32 r0 = (u32)__shfl_xor((int)send0, 32, 64);
                u32 r1 = (u32)__shfl_xor((int)send1, 32, 64);
                union { u32 wd[4]; bf16x8 v; } pu;
                pu.wd[0] = hx ? r0 : pk[b2][2 * s][0];
                pu.wd[1] = hx ? r1 : pk[b2][2 * s][1];
                pu.wd[2] = hx ? pk[b2][2 * s + 1][0] : r0;
                pu.wd[3] = hx ? pk[b2][2 * s + 1][1] : r1;
#pragma unroll
                for (int dblk = 0; dblk < 4; dblk++) {
                    int vrow = dblk * 32 + l31;
                    int vbyte = (vrow * 128 + t4 * 32 + hx * 16) ^ ((l31 & 7) << 4);
                    bf16x8 vf = *(const bf16x8*)(sVt + vbyte);
                    o[dblk] = __builtin_amdgcn_mfma_f32_32x32x16_bf16(vf, pu.v, o[dblk], 0, 0, 0);
                }
            }
            __builtin_amdgcn_s_setprio(0);
        }
    }

    // ---- merge (2 passes, 34.3KB buffer): B publishes (m,l,O); A combines ----
    __syncthreads();   // all staging reads done; safe to overlay merge buffers
#pragma unroll 1
    for (int pass = 0; pass < 2; ++pass) {
        if (grp == 1 && (w >> 1) == pass) {
            const int r0 = (w & 1) * 32 + l31;
#pragma unroll
            for (int dblk = 0; dblk < 4; dblk++)
#pragma unroll
                for (int rg = 0; rg < 4; rg++) {
                    int d0 = dblk * 32 + rg * 8 + hx * 4;
                    f32x4 v;
                    v[0] = o[dblk][rg * 4 + 0]; v[1] = o[dblk][rg * 4 + 1];
                    v[2] = o[dblk][rg * 4 + 2]; v[3] = o[dblk][rg * 4 + 3];
                    *(f32x4*)&mO[r0 * 132 + d0] = v;
                }
            if (hx == 0) {
                mml[r0 * 2 + 0] = mi;
                mml[r0 * 2 + 1] = li;
            }
        }
        __syncthreads();
        if (grp == 0 && (w >> 1) == pass) {
            const int r0 = (w & 1) * 32 + l31;
            float mB = mml[r0 * 2 + 0];
            float lB = mml[r0 * 2 + 1];
            float m = fmaxf(mi, mB);
            float a0 = exp2_fast((mi - m) * C1);
            float a1 = exp2_fast((mB - m) * C1);
            float linv = 1.f / (li * a0 + lB * a1);
            u16* op = obuf + (size_t)(rowbase + q0 + w * 32 + l31) * 2048 + hh * 128;
#pragma unroll
            for (int dblk = 0; dblk < 4; dblk++)
#pragma unroll
                for (int rg = 0; rg < 4; rg++) {
                    int d0 = dblk * 32 + rg * 8 + hx * 4;
                    f32x4 ob = *(const f32x4*)&mO[r0 * 132 + d0];
                    ushort4 ov;
                    ov.x = f2bf((o[dblk][rg * 4 + 0] * a0 + ob[0] * a1) * linv);
                    ov.y = f2bf((o[dblk][rg * 4 + 1] * a0 + ob[1] * a1) * linv);
                    ov.z = f2bf((o[dblk][rg * 4 + 2] * a0 + ob[2] * a1) * linv);
                    ov.w = f2bf((o[dblk][rg * 4 + 3] * a0 + ob[3] * a1) * linv);
                    *(ushort4*)(op + d0) = ov;
                }
        }
        __syncthreads();
    }
}

// ---------------- launch ----------------
extern "C" void kernel_launch(void* const* d_in, const int* in_sizes, int n_in,
                              void* d_out, int out_size, void* d_ws, size_t ws_size,
                              hipStream_t stream) {
    const float* x        = (const float*)d_in[0];
    const float* q_down_w = (const float*)d_in[1];
    const float* q_down_b = (const float*)d_in[2];
    const float* q_norm_w = (const float*)d_in[3];
    const float* q_up_w   = (const float*)d_in[4];
    const float* q_up_b   = (const float*)d_in[5];
    const float* kv_down_w= (const float*)d_in[6];
    const float* kv_down_b= (const float*)d_in[7];
    const float* kv_norm_w= (const float*)d_in[8];
    const float* kv_up_w  = (const float*)d_in[9];
    const float* kv_up_b  = (const float*)d_in[10];
    const float* k_rope_w = (const float*)d_in[11];
    const float* k_rope_b = (const float*)d_in[12];
    const float* out_w    = (const float*)d_in[13];
    const float* out_b    = (const float*)d_in[14];

    char* ws = (char*)d_ws;
    u16* xbf    = (u16*)(ws + 0);          // 16.78 MB ; later reused as vT
    u16* wcat   = (u16*)(ws + 16777216);   // 10.49 MB (2560x2048 bf16)
    u16* quw    = (u16*)(ws + 27262976);   // 4.19 MB
    u16* kvuw   = (u16*)(ws + 31457280);   // 3.15 MB
    u16* outw   = (u16*)(ws + 34603008);   // 8.39 MB
    float* bcat = (float*)(ws + 42991616); // 10 KB (pad to 16 KB)
    float* dcat = (float*)(ws + 43008000); // 25.17 MB (4096x1536 f32); reused as attnbuf
    u16* cq     = (u16*)(ws + 68173824);   // 8.39 MB
    u16* ckv    = (u16*)(ws + 76562432);   // 4.19 MB
    u16* qbuf   = (u16*)(ws + 80756736);   // 16.78 MB
    u16* kvbuf  = (u16*)(ws + 97533952);   // 25.17 MB
    u16* krbuf  = (u16*)(ws + 122699776);  // 8.39 MB  (end 131,088,384)
    u16* vT     = (u16*)(ws + 0);          // alias xbf (dead after gemm_down)
    u16* attnbuf= (u16*)(ws + 43008000);   // alias dcat (dead after rmsnorms)

    cvt_all<<<20992, 256, 0, stream>>>(
        x, xbf,
        q_down_w,  wcat,
        kv_down_w, wcat + 1024 * 2048,
        k_rope_w,  wcat + 1536 * 2048,
        q_up_w,    quw,
        kv_up_w,   kvuw,
        out_w,     outw);
    build_bcat<<<10, 256, 0, stream>>>(q_down_b, kv_down_b, k_rope_b, bcat);

    // fused down projections: x @ [q_down|kv_down|k_rope]^T
    gemm_down<<<dim3(20, 32), 256, 0, stream>>>(xbf, wcat, bcat, dcat, krbuf);
    rmsnorm_bf16<1024><<<MROWS, 256, 0, stream>>>(dcat, 1536, q_norm_w, cq);
    rmsnorm_bf16<512><<<MROWS, 256, 0, stream>>>(dcat + 1024, 1536, kv_norm_w, ckv);
    // up projections
    gemm_bt<u16><<<dim3(16, 32), 256, 0, stream>>>(cq, quw, q_up_b, qbuf, MROWS, 2048, 1024);
    gemm_bt<u16><<<dim3(24, 32), 256, 0, stream>>>(ckv, kvuw, kv_up_b, kvbuf, MROWS, 3072, 512);
    // V transpose (vT aliases xbf; xbf dead after gemm_down)
    transpose_v<<<dim3(64, 32), 256, 0, stream>>>(kvbuf, vT);
    // attention: 512 blocks x 512 threads, K-split, 64KB LDS -> 2 blocks/CU
    mla_attn<<<dim3(32, 16), 512, 0, stream>>>(qbuf, kvbuf, krbuf, vT, attnbuf);
    // output projection
    gemm_bt<float><<<dim3(16, 32), 256, 0, stream>>>(attnbuf, outw, out_b, (float*)d_out, MROWS, 2048, 2048);
}

// Round 16
// 247.396 us; speedup vs baseline: 1.8081x; 1.0435x over previous
//
#include <hip/hip_runtime.h>
#include <hip/hip_bf16.h>

typedef __attribute__((ext_vector_type(8))) short bf16x8;
typedef __attribute__((ext_vector_type(4))) float f32x4;
typedef __attribute__((ext_vector_type(16))) float f32x16;
typedef unsigned short u16;
typedef unsigned int u32;

#define RMS_EPS 1.1920929e-07f

constexpr int Bb = 2, Ss = 2048, DM = 2048, NH = 16;
constexpr int MROWS = Bb * Ss; // 4096

__device__ __forceinline__ u16 f2bf(float f) {
    __hip_bfloat16 h = __float2bfloat16(f);
    return *reinterpret_cast<u16*>(&h);
}

__device__ __forceinline__ float exp2_fast(float x) {
    float r; asm("v_exp_f32 %0, %1" : "=v"(r) : "v"(x)); return r;
}

__device__ __forceinline__ void gload16(const void* g, void* l) {
    __builtin_amdgcn_global_load_lds(
        (const __attribute__((address_space(1))) unsigned int*)g,
        (__attribute__((address_space(3))) unsigned int*)l, 16, 0, 0);
}

// ------- merged fp32 -> bf16 convert (7 segments) + bias concat tail block ----
__global__ __launch_bounds__(256) void cvt_all(
    const float* __restrict__ s0, u16* __restrict__ d0,
    const float* __restrict__ s1, u16* __restrict__ d1,
    const float* __restrict__ s2, u16* __restrict__ d2,
    const float* __restrict__ s3, u16* __restrict__ d3,
    const float* __restrict__ s4, u16* __restrict__ d4,
    const float* __restrict__ s5, u16* __restrict__ d5,
    const float* __restrict__ s6, u16* __restrict__ d6,
    const float* __restrict__ qb, const float* __restrict__ kvb,
    const float* __restrict__ krb, float* __restrict__ bcat)
{
    int i = blockIdx.x * 256 + threadIdx.x;   // float4 index; data covers 5373952
    if (i >= 5373952) {                       // tail block: bias concat (2560 = 10*256)
        int t = threadIdx.x;
#pragma unroll
        for (int s = 0; s < 10; s++) {
            int j = t + s * 256;
            float v = (j < 1024) ? qb[j] : (j < 1536) ? kvb[j - 1024] : krb[j - 1536];
            bcat[j] = v;
        }
        return;
    }
    const float* s; u16* d; int off;
    if (i < 2097152)      { s = s0; d = d0; off = 0; }
    else if (i < 2621440) { s = s1; d = d1; off = 2097152; }
    else if (i < 2883584) { s = s2; d = d2; off = 2621440; }
    else if (i < 3407872) { s = s3; d = d3; off = 2883584; }
    else if (i < 3932160) { s = s4; d = d4; off = 3407872; }
    else if (i < 4325376) { s = s5; d = d5; off = 3932160; }
    else                  { s = s6; d = d6; off = 4325376; }
    int j = i - off;
    float4 v = reinterpret_cast<const float4*>(s)[j];
    ushort4 o;
    o.x = f2bf(v.x); o.y = f2bf(v.y); o.z = f2bf(v.z); o.w = f2bf(v.w);
    reinterpret_cast<ushort4*>(d)[j] = o;
}

// XCD-chunked bijective block remap (T1). Requires nwg % 8 == 0.
__device__ __forceinline__ void xcd_remap(int& bx, int& by) {
    int nx = gridDim.x, ny = gridDim.y;
    int nwg = nx * ny;
    if ((nwg & 7) != 0) return;
    int flat = blockIdx.x + nx * blockIdx.y;
    int chunk = nwg >> 3;
    int wg = (flat & 7) * chunk + (flat >> 3);
    by = wg % ny;          // M-tile fastest within an XCD chunk
    bx = wg / ny;          // few N-columns per XCD -> B-panel L2 reuse
}

// ---------------- GEMM: C(M,N) = A(M,K) * Bt(N,K)^T + bias ----------------
// 2-phase double-buffered: STAGE(t+1) issued BEFORE compute(t); 1 barrier/K-step.
template <typename OutT>
__global__ __launch_bounds__(256) void gemm_bt(
    const u16* __restrict__ A, const u16* __restrict__ Bt,
    const float* __restrict__ bias, OutT* __restrict__ C,
    int M, int N, int K)
{
    __shared__ alignas(16) u16 sA[2][128 * 32];
    __shared__ alignas(16) u16 sB[2][128 * 32];
    const int tid = threadIdx.x;
    const int lane = tid & 63;
    const int w = tid >> 6;
    const int wr = w >> 1, wc = w & 1;
    const int l16 = lane & 15, lq = lane >> 4;
    int bx = blockIdx.x, by = blockIdx.y;
    xcd_remap(bx, by);
    const int tileM = by * 128;
    const int tileN = bx * 128;

    f32x4 acc[4][4];
#pragma unroll
    for (int m = 0; m < 4; m++)
#pragma unroll
        for (int n = 0; n < 4; n++)
#pragma unroll
            for (int r = 0; r < 4; r++) acc[m][n][r] = 0.f;

    const int srow = w * 16 + (lane >> 2);
    const int scol = (lane & 3) * 8;
    const u16* gA0 = A + (size_t)(tileM + srow) * K + scol;
    const u16* gA1 = A + (size_t)(tileM + srow + 64) * K + scol;
    const u16* gB0 = Bt + (size_t)(tileN + srow) * K + scol;
    const u16* gB1 = Bt + (size_t)(tileN + srow + 64) * K + scol;
    u16* lA0 = &sA[0][0] + w * 512;
    u16* lA1 = &sA[0][0] + 2048 + w * 512;
    u16* lB0 = &sB[0][0] + w * 512;
    u16* lB1 = &sB[0][0] + 2048 + w * 512;

    int aoff[4], boff[4];
#pragma unroll
    for (int m = 0; m < 4; m++) aoff[m] = (wr * 64 + m * 16 + l16) * 32 + lq * 8;
#pragma unroll
    for (int n = 0; n < 4; n++) boff[n] = (wc * 64 + n * 16 + l16) * 32 + lq * 8;

    const int nk = K >> 5;
    gload16(gA0, lA0);
    gload16(gA1, lA1);
    gload16(gB0, lB0);
    gload16(gB1, lB1);
    __syncthreads();
    int cur = 0;
    for (int kk = 0; kk < nk; ++kk) {
        if (kk + 1 < nk) {
            int nb = (cur ^ 1) * 4096;
            const u16* a0 = gA0 + (size_t)(kk + 1) * 32;
            const u16* a1 = gA1 + (size_t)(kk + 1) * 32;
            const u16* b0 = gB0 + (size_t)(kk + 1) * 32;
            const u16* b1 = gB1 + (size_t)(kk + 1) * 32;
            gload16(a0, lA0 + nb);
            gload16(a1, lA1 + nb);
            gload16(b0, lB0 + nb);
            gload16(b1, lB1 + nb);
        }
        const u16* bA = &sA[0][0] + cur * 4096;
        const u16* bB = &sB[0][0] + cur * 4096;
        bf16x8 af[4], bfr[4];
#pragma unroll
        for (int m = 0; m < 4; m++) af[m] = *(const bf16x8*)&bA[aoff[m]];
#pragma unroll
        for (int n = 0; n < 4; n++) bfr[n] = *(const bf16x8*)&bB[boff[n]];
        __builtin_amdgcn_s_setprio(1);
#pragma unroll
        for (int m = 0; m < 4; m++)
#pragma unroll
            for (int n = 0; n < 4; n++)
                acc[m][n] = __builtin_amdgcn_mfma_f32_16x16x32_bf16(af[m], bfr[n], acc[m][n], 0, 0, 0);
        __builtin_amdgcn_s_setprio(0);
        __syncthreads();
        cur ^= 1;
    }

#pragma unroll
    for (int n = 0; n < 4; n++) {
        int col = tileN + wc * 64 + n * 16 + l16;
        float bv = bias ? bias[col] : 0.f;
#pragma unroll
        for (int m = 0; m < 4; m++) {
            int rowb = tileM + wr * 64 + m * 16 + (lq << 2);
#pragma unroll
            for (int r = 0; r < 4; r++) {
                float v = acc[m][n][r] + bv;
                if constexpr (sizeof(OutT) == 2)
                    C[(size_t)(rowb + r) * N + col] = (OutT)f2bf(v);
                else
                    C[(size_t)(rowb + r) * N + col] = (OutT)v;
            }
        }
    }
}

// ---------------- kv_up GEMM with fused V transpose ----------------
// C(M,3072) = A(M,512) * Bt^T + bias. Per-head 192 cols: knope(64) -> kvbuf
// (scalar, row-major); v(128) -> vT DIRECTLY TRANSPOSED: the 4 accumulator rows
// are consecutive tokens -> one aligned ushort4 per (m,n). Replaces the
// separate transpose_v kernel and the dead kvbuf V-writes.
__global__ __launch_bounds__(256) void gemm_kvup(
    const u16* __restrict__ A, const u16* __restrict__ Bt,
    const float* __restrict__ bias, u16* __restrict__ kvbuf,
    u16* __restrict__ vT)
{
    constexpr int K = 512, N = 3072;
    __shared__ alignas(16) u16 sA[2][128 * 32];
    __shared__ alignas(16) u16 sB[2][128 * 32];
    const int tid = threadIdx.x;
    const int lane = tid & 63;
    const int w = tid >> 6;
    const int wr = w >> 1, wc = w & 1;
    const int l16 = lane & 15, lq = lane >> 4;
    int bx = blockIdx.x, by = blockIdx.y;
    xcd_remap(bx, by);
    const int tileM = by * 128;
    const int tileN = bx * 128;

    f32x4 acc[4][4];
#pragma unroll
    for (int m = 0; m < 4; m++)
#pragma unroll
        for (int n = 0; n < 4; n++)
#pragma unroll
            for (int r = 0; r < 4; r++) acc[m][n][r] = 0.f;

    const int srow = w * 16 + (lane >> 2);
    const int scol = (lane & 3) * 8;
    const u16* gA0 = A + (size_t)(tileM + srow) * K + scol;
    const u16* gA1 = A + (size_t)(tileM + srow + 64) * K + scol;
    const u16* gB0 = Bt + (size_t)(tileN + srow) * K + scol;
    const u16* gB1 = Bt + (size_t)(tileN + srow + 64) * K + scol;
    u16* lA0 = &sA[0][0] + w * 512;
    u16* lA1 = &sA[0][0] + 2048 + w * 512;
    u16* lB0 = &sB[0][0] + w * 512;
    u16* lB1 = &sB[0][0] + 2048 + w * 512;

    int aoff[4], boff[4];
#pragma unroll
    for (int m = 0; m < 4; m++) aoff[m] = (wr * 64 + m * 16 + l16) * 32 + lq * 8;
#pragma unroll
    for (int n = 0; n < 4; n++) boff[n] = (wc * 64 + n * 16 + l16) * 32 + lq * 8;

    const int nk = K >> 5;
    gload16(gA0, lA0);
    gload16(gA1, lA1);
    gload16(gB0, lB0);
    gload16(gB1, lB1);
    __syncthreads();
    int cur = 0;
    for (int kk = 0; kk < nk; ++kk) {
        if (kk + 1 < nk) {
            int nb = (cur ^ 1) * 4096;
            const u16* a0 = gA0 + (size_t)(kk + 1) * 32;
            const u16* a1 = gA1 + (size_t)(kk + 1) * 32;
            const u16* b0 = gB0 + (size_t)(kk + 1) * 32;
            const u16* b1 = gB1 + (size_t)(kk + 1) * 32;
            gload16(a0, lA0 + nb);
            gload16(a1, lA1 + nb);
            gload16(b0, lB0 + nb);
            gload16(b1, lB1 + nb);
        }
        const u16* bA = &sA[0][0] + cur * 4096;
        const u16* bB = &sB[0][0] + cur * 4096;
        bf16x8 af[4], bfr[4];
#pragma unroll
        for (int m = 0; m < 4; m++) af[m] = *(const bf16x8*)&bA[aoff[m]];
#pragma unroll
        for (int n = 0; n < 4; n++) bfr[n] = *(const bf16x8*)&bB[boff[n]];
        __builtin_amdgcn_s_setprio(1);
#pragma unroll
        for (int m = 0; m < 4; m++)
#pragma unroll
            for (int n = 0; n < 4; n++)
                acc[m][n] = __builtin_amdgcn_mfma_f32_16x16x32_bf16(af[m], bfr[n], acc[m][n], 0, 0, 0);
        __builtin_amdgcn_s_setprio(0);
        __syncthreads();
        cur ^= 1;
    }

#pragma unroll
    for (int n = 0; n < 4; n++) {
        int col = tileN + wc * 64 + n * 16 + l16;
        float bv = bias[col];
        int h = col / 192;
        int dd = col - h * 192;
#pragma unroll
        for (int m = 0; m < 4; m++) {
            int rowb = tileM + wr * 64 + m * 16 + (lq << 2);
            if (dd < 64) {   // knope -> kvbuf, row-major scalar (as before)
#pragma unroll
                for (int r = 0; r < 4; r++)
                    kvbuf[(size_t)(rowb + r) * N + col] = f2bf(acc[m][n][r] + bv);
            } else {         // v -> vT transposed: 4 consecutive tokens = ushort4
                int d = dd - 64;
                ushort4 ov;
                ov.x = f2bf(acc[m][n][0] + bv);
                ov.y = f2bf(acc[m][n][1] + bv);
                ov.z = f2bf(acc[m][n][2] + bv);
                ov.w = f2bf(acc[m][n][3] + bv);
                *(ushort4*)(vT + (size_t)(h * 128 + d) * MROWS + rowb) = ov;
            }
        }
    }
}

// ---------------- fused down-proj GEMM: N=2560 (1024 q | 512 kv | 1024 rope) ----
// Same 2-phase schedule as gemm_bt.
__global__ __launch_bounds__(256) void gemm_down(
    const u16* __restrict__ A, const u16* __restrict__ Bt,
    const float* __restrict__ bcat, float* __restrict__ dcat,
    u16* __restrict__ krbuf)
{
    constexpr int K = 2048;
    __shared__ alignas(16) u16 sA[2][128 * 32];
    __shared__ alignas(16) u16 sB[2][128 * 32];
    const int tid = threadIdx.x;
    const int lane = tid & 63;
    const int w = tid >> 6;
    const int wr = w >> 1, wc = w & 1;
    const int l16 = lane & 15, lq = lane >> 4;
    int bx = blockIdx.x, by = blockIdx.y;
    xcd_remap(bx, by);
    const int tileM = by * 128;
    const int tileN = bx * 128;

    f32x4 acc[4][4];
#pragma unroll
    for (int m = 0; m < 4; m++)
#pragma unroll
        for (int n = 0; n < 4; n++)
#pragma unroll
            for (int r = 0; r < 4; r++) acc[m][n][r] = 0.f;

    const int srow = w * 16 + (lane >> 2);
    const int scol = (lane & 3) * 8;
    const u16* gA0 = A + (size_t)(tileM + srow) * K + scol;
    const u16* gA1 = A + (size_t)(tileM + srow + 64) * K + scol;
    const u16* gB0 = Bt + (size_t)(tileN + srow) * K + scol;
    const u16* gB1 = Bt + (size_t)(tileN + srow + 64) * K + scol;
    u16* lA0 = &sA[0][0] + w * 512;
    u16* lA1 = &sA[0][0] + 2048 + w * 512;
    u16* lB0 = &sB[0][0] + w * 512;
    u16* lB1 = &sB[0][0] + 2048 + w * 512;

    int aoff[4], boff[4];
#pragma unroll
    for (int m = 0; m < 4; m++) aoff[m] = (wr * 64 + m * 16 + l16) * 32 + lq * 8;
#pragma unroll
    for (int n = 0; n < 4; n++) boff[n] = (wc * 64 + n * 16 + l16) * 32 + lq * 8;

    const int nk = K >> 5;
    gload16(gA0, lA0);
    gload16(gA1, lA1);
    gload16(gB0, lB0);
    gload16(gB1, lB1);
    __syncthreads();
    int cur = 0;
    for (int kk = 0; kk < nk; ++kk) {
        if (kk + 1 < nk) {
            int nb = (cur ^ 1) * 4096;
            const u16* a0 = gA0 + (size_t)(kk + 1) * 32;
            const u16* a1 = gA1 + (size_t)(kk + 1) * 32;
            const u16* b0 = gB0 + (size_t)(kk + 1) * 32;
            const u16* b1 = gB1 + (size_t)(kk + 1) * 32;
            gload16(a0, lA0 + nb);
            gload16(a1, lA1 + nb);
            gload16(b0, lB0 + nb);
            gload16(b1, lB1 + nb);
        }
        const u16* bA = &sA[0][0] + cur * 4096;
        const u16* bB = &sB[0][0] + cur * 4096;
        bf16x8 af[4], bfr[4];
#pragma unroll
        for (int m = 0; m < 4; m++) af[m] = *(const bf16x8*)&bA[aoff[m]];
#pragma unroll
        for (int n = 0; n < 4; n++) bfr[n] = *(const bf16x8*)&bB[boff[n]];
        __builtin_amdgcn_s_setprio(1);
#pragma unroll
        for (int m = 0; m < 4; m++)
#pragma unroll
            for (int n = 0; n < 4; n++)
                acc[m][n] = __builtin_amdgcn_mfma_f32_16x16x32_bf16(af[m], bfr[n], acc[m][n], 0, 0, 0);
        __builtin_amdgcn_s_setprio(0);
        __syncthreads();
        cur ^= 1;
    }

    const bool isrope = (tileN >= 1536);
#pragma unroll
    for (int n = 0; n < 4; n++) {
        int col = tileN + wc * 64 + n * 16 + l16;
        float bv = bcat[col];
#pragma unroll
        for (int m = 0; m < 4; m++) {
            int rowb = tileM + wr * 64 + m * 16 + (lq << 2);
#pragma unroll
            for (int r = 0; r < 4; r++) {
                float v = acc[m][n][r] + bv;
                if (!isrope) dcat[(size_t)(rowb + r) * 1536 + col] = v;
                else         krbuf[(size_t)(rowb + r) * 1024 + (col - 1536)] = f2bf(v);
            }
        }
    }
}

// ---------------- RMS norm (row-wise, strided in), fp32 in -> bf16 out --------
template <int C>
__global__ __launch_bounds__(256) void rmsnorm_bf16(
    const float* __restrict__ in, int istride, const float* __restrict__ wgt, u16* __restrict__ out)
{
    const int row = blockIdx.x;
    const int tid = threadIdx.x;
    constexpr int PER = C / 256;
    const float* p = in + (size_t)row * istride;
    float v[PER];
    float ss = 0.f;
#pragma unroll
    for (int i = 0; i < PER; i++) { v[i] = p[tid + i * 256]; ss += v[i] * v[i]; }
#pragma unroll
    for (int o = 32; o; o >>= 1) ss += __shfl_xor(ss, o, 64);
    __shared__ float red[4];
    if ((tid & 63) == 0) red[tid >> 6] = ss;
    __syncthreads();
    float tot = red[0] + red[1] + red[2] + red[3];
    float inv = rsqrtf(tot / (float)C + RMS_EPS);
    u16* q = out + (size_t)row * C;
#pragma unroll
    for (int i = 0; i < PER; i++) {
        int c = tid + i * 256;
        q[c] = f2bf(v[i] * inv * wgt[c]);
    }
}

// ---------------- causal flash attention: in-block K-split, 8 waves ----------
// Block = (bh, qt), 512 threads, __launch_bounds__(512,2). Waves 0-3 (group A)
// process k-tiles [0, qt+1); waves 4-7 (group B) process [qt+1, 2qt+2).
// LDS 64 KB (staging 4x16KB; merge overlays first 34.3KB in TWO passes).
// qt = 15 - y: longest blocks first.
__global__ __launch_bounds__(512, 2) void mla_attn(
    const u16* __restrict__ qbuf,   // (4096, 2048) head-major h*128
    const u16* __restrict__ kvbuf,  // (4096, 3072) per head 192: knope(64) [v dead]
    const u16* __restrict__ krbuf,  // (4096, 1024) per head 64
    const u16* __restrict__ vT,     // (h*128+d, 4096 tokens)
    u16* __restrict__ obuf)         // (4096, 2048)
{
    const int bh = blockIdx.x;
    const int qt = 15 - blockIdx.y;   // longest blocks dispatch first
    const int b = bh >> 4, hh = bh & 15;
    const int tid = threadIdx.x, lane = tid & 63;
    const int w8 = tid >> 6;
    const int grp = w8 >> 2;        // 0 = A (low k half), 1 = B (high k half)
    const int w = w8 & 3;           // wave-in-group; q rows w*32..w*32+31
    const int l31 = lane & 31, hx = lane >> 5;
    const int tg = tid & 255;       // thread-in-group

    __shared__ alignas(16) char smem[65536];
    char* sK  = smem + grp * 16384;            // [64][128] bf16, XOR-swizzled
    char* sVt = smem + 32768 + grp * 16384;    // [128][64] bf16, XOR-swizzled
    float* mO  = (float*)smem;                 // merge (2 passes): [2 wv][32 q][132] f32
    float* mml = (float*)(smem + 33792);       // merge: [2 wv][32 q][2] f32

    const int rowbase = b * Ss;
    const int q0 = qt * 128;
    const int niter = qt + 1;
    const int kbase = grp ? niter : 0;

    const int sr = tg >> 2, sc = (tg & 3) * 32;   // K staging (group-local)
    const int vd = tg >> 1, vh = (tg & 1) * 32;   // V staging (group-local)
    const float C1 = 0.12751742f;    // softmax_scale * log2(e)
    const float THRR = 90.5f;        // defer-max threshold (raw score units)

    // Q fragments: lane (q=l31, hx) needs d-chunks (2c + hx), c = 0..7
    bf16x8 qf[8];
    {
        const u16* qp = qbuf + (size_t)(rowbase + q0 + w * 32 + l31) * 2048 + hh * 128;
#pragma unroll
        for (int c = 0; c < 8; c++) qf[c] = *(const bf16x8*)(qp + (2 * c + hx) * 8);
    }
    float mi = -3e38f, li = 0.f;
    f32x16 o[4];
#pragma unroll
    for (int d = 0; d < 4; d++)
#pragma unroll
        for (int i = 0; i < 16; i++) o[d][i] = 0.f;

    bf16x8 kr[4], vr[4];
    {   // prologue: tile kbase -> regs
        const int krow = rowbase + kbase * 64 + sr;
        const u16* src = (sc < 64)
            ? kvbuf + (size_t)krow * 3072 + hh * 192 + sc
            : krbuf + (size_t)krow * 1024 + hh * 64 + (sc - 64);
#pragma unroll
        for (int j = 0; j < 4; j++) kr[j] = *(const bf16x8*)(src + j * 8);
        const u16* vsrc = vT + (size_t)(hh * 128 + vd) * MROWS + rowbase + kbase * 64 + vh;
#pragma unroll
        for (int j = 0; j < 4; j++) vr[j] = *(const bf16x8*)(vsrc + j * 8);
    }

#pragma unroll 1
    for (int t = 0; t < niter; ++t) {
        const int kt = kbase + t;
        __syncthreads();
#pragma unroll
        for (int j = 0; j < 4; j++) {
            int byteoff = sr * 256 + (sc + j * 8) * 2;
            *(bf16x8*)(sK + (byteoff ^ ((sr & 7) << 4))) = kr[j];
        }
#pragma unroll
        for (int j = 0; j < 4; j++) {
            int byteoff = vd * 128 + (vh + j * 8) * 2;
            *(bf16x8*)(sVt + (byteoff ^ ((vd & 7) << 4))) = vr[j];
        }
        __syncthreads();
        if (t + 1 < niter) {   // prefetch next tile into regs (hides under compute)
            const int krow = rowbase + (kt + 1) * 64 + sr;
            const u16* src = (sc < 64)
                ? kvbuf + (size_t)krow * 3072 + hh * 192 + sc
                : krbuf + (size_t)krow * 1024 + hh * 64 + (sc - 64);
#pragma unroll
            for (int j = 0; j < 4; j++) kr[j] = *(const bf16x8*)(src + j * 8);
            const u16* vsrc = vT + (size_t)(hh * 128 + vd) * MROWS + rowbase + (kt + 1) * 64 + vh;
#pragma unroll
            for (int j = 0; j < 4; j++) vr[j] = *(const bf16x8*)(vsrc + j * 8);
        }

        // wave-dead skip: this wave's q range is [q0+32w, q0+32w+31]
        const bool alive = (kt * 64) <= (q0 + w * 32 + 31);
        if (alive) {
            // QK^T swapped: A=K(32k x 16d), B=Q(16d x 32q) -> D[k][q], q=l31
            f32x16 scf[2];
#pragma unroll
            for (int b2 = 0; b2 < 2; b2++)
#pragma unroll
                for (int i = 0; i < 16; i++) scf[b2][i] = 0.f;
            __builtin_amdgcn_s_setprio(1);
#pragma unroll
            for (int s = 0; s < 8; s++) {
#pragma unroll
                for (int b2 = 0; b2 < 2; b2++) {
                    int krow = b2 * 32 + l31;
                    int kbyte = (krow * 256 + s * 32 + hx * 16) ^ ((l31 & 7) << 4);
                    bf16x8 kf = *(const bf16x8*)(sK + kbyte);
                    scf[b2] = __builtin_amdgcn_mfma_f32_32x32x16_bf16(kf, qf[s], scf[b2], 0, 0, 0);
                }
            }
            __builtin_amdgcn_s_setprio(0);

            // causal mask (only diagonal-adjacent tiles for this wave)
            if (kt * 64 + 63 > q0 + w * 32) {
                const int qg = q0 + w * 32 + l31;
#pragma unroll
                for (int b2 = 0; b2 < 2; b2++)
#pragma unroll
                    for (int rg = 0; rg < 16; rg++) {
                        int kg = kt * 64 + b2 * 32 + (rg & 3) + 8 * (rg >> 2) + 4 * hx;
                        if (kg > qg) scf[b2][rg] = -3e38f;
                    }
            }
            // online softmax: in-lane over 32 vals + partner exchange
            float mx = mi;
#pragma unroll
            for (int b2 = 0; b2 < 2; b2++)
#pragma unroll
                for (int rg = 0; rg < 16; rg++) mx = fmaxf(mx, scf[b2][rg]);
            mx = fmaxf(mx, __shfl_xor(mx, 32, 64));
            if (!__all(mx - mi <= THRR)) {   // T13 defer-max
                float f = exp2_fast((mi - mx) * C1);
                li *= f;
#pragma unroll
                for (int d = 0; d < 4; d++)
#pragma unroll
                    for (int i = 0; i < 16; i++) o[d][i] *= f;
                mi = mx;
            }
            float mc = mi * C1;
            float rs = 0.f;
#pragma unroll
            for (int b2 = 0; b2 < 2; b2++)
#pragma unroll
                for (int rg = 0; rg < 16; rg++) {
                    float pv = exp2_fast(__fmaf_rn(scf[b2][rg], C1, -mc));
                    scf[b2][rg] = pv;
                    rs += pv;
                }
            rs += __shfl_xor(rs, 32, 64);
            li += rs;

            // pack P -> bf16 pairs: pk[b][g] covers rows {8g..8g+3} + 4*hx
            u32 pk[2][4][2];
#pragma unroll
            for (int b2 = 0; b2 < 2; b2++)
#pragma unroll
                for (int g = 0; g < 4; g++) {
                    pk[b2][g][0] = (u32)f2bf(scf[b2][4 * g + 0]) | ((u32)f2bf(scf[b2][4 * g + 1]) << 16);
                    pk[b2][g][1] = (u32)f2bf(scf[b2][4 * g + 2]) | ((u32)f2bf(scf[b2][4 * g + 3]) << 16);
                }

            // PV swapped: A=V^T(32d x 16k), B=P^T(16k x 32q) -> O^T[d][q]
            __builtin_amdgcn_s_setprio(1);
#pragma unroll
            for (int t4 = 0; t4 < 4; t4++) {
                const int b2 = t4 >> 1, s = t4 & 1;
                u32 send0 = hx ? pk[b2][2 * s][0] : pk[b2][2 * s + 1][0];
                u32 send1 = hx ? pk[b2][2 * s][1] : pk[b2][2 * s + 1][1];
                u32 r0 = (u32)__shfl_xor((int)send0, 32, 64);
                u32 r1 = (u32)__shfl_xor((int)send1, 32, 64);
                union { u32 wd[4]; bf16x8 v; } pu;
                pu.wd[0] = hx ? r0 : pk[b2][2 * s][0];
                pu.wd[1] = hx ? r1 : pk[b2][2 * s][1];
                pu.wd[2] = hx ? pk[b2][2 * s + 1][0] : r0;
                pu.wd[3] = hx ? pk[b2][2 * s + 1][1] : r1;
#pragma unroll
                for (int dblk = 0; dblk < 4; dblk++) {
                    int vrow = dblk * 32 + l31;
                    int vbyte = (vrow * 128 + t4 * 32 + hx * 16) ^ ((l31 & 7) << 4);
                    bf16x8 vf = *(const bf16x8*)(sVt + vbyte);
                    o[dblk] = __builtin_amdgcn_mfma_f32_32x32x16_bf16(vf, pu.v, o[dblk], 0, 0, 0);
                }
            }
            __builtin_amdgcn_s_setprio(0);
        }
    }

    // ---- merge (2 passes, 34.3KB buffer): B publishes (m,l,O); A combines ----
    __syncthreads();   // all staging reads done; safe to overlay merge buffers
#pragma unroll 1
    for (int pass = 0; pass < 2; ++pass) {
        if (grp == 1 && (w >> 1) == pass) {
            const int r0 = (w & 1) * 32 + l31;
#pragma unroll
            for (int dblk = 0; dblk < 4; dblk++)
#pragma unroll
                for (int rg = 0; rg < 4; rg++) {
                    int d0 = dblk * 32 + rg * 8 + hx * 4;
                    f32x4 v;
                    v[0] = o[dblk][rg * 4 + 0]; v[1] = o[dblk][rg * 4 + 1];
                    v[2] = o[dblk][rg * 4 + 2]; v[3] = o[dblk][rg * 4 + 3];
                    *(f32x4*)&mO[r0 * 132 + d0] = v;
                }
            if (hx == 0) {
                mml[r0 * 2 + 0] = mi;
                mml[r0 * 2 + 1] = li;
            }
        }
        __syncthreads();
        if (grp == 0 && (w >> 1) == pass) {
            const int r0 = (w & 1) * 32 + l31;
            float mB = mml[r0 * 2 + 0];
            float lB = mml[r0 * 2 + 1];
            float m = fmaxf(mi, mB);
            float a0 = exp2_fast((mi - m) * C1);
            float a1 = exp2_fast((mB - m) * C1);
            float linv = 1.f / (li * a0 + lB * a1);
            u16* op = obuf + (size_t)(rowbase + q0 + w * 32 + l31) * 2048 + hh * 128;
#pragma unroll
            for (int dblk = 0; dblk < 4; dblk++)
#pragma unroll
                for (int rg = 0; rg < 4; rg++) {
                    int d0 = dblk * 32 + rg * 8 + hx * 4;
                    f32x4 ob = *(const f32x4*)&mO[r0 * 132 + d0];
                    ushort4 ov;
                    ov.x = f2bf((o[dblk][rg * 4 + 0] * a0 + ob[0] * a1) * linv);
                    ov.y = f2bf((o[dblk][rg * 4 + 1] * a0 + ob[1] * a1) * linv);
                    ov.z = f2bf((o[dblk][rg * 4 + 2] * a0 + ob[2] * a1) * linv);
                    ov.w = f2bf((o[dblk][rg * 4 + 3] * a0 + ob[3] * a1) * linv);
                    *(ushort4*)(op + d0) = ov;
                }
        }
        __syncthreads();
    }
}

// ---------------- launch ----------------
extern "C" void kernel_launch(void* const* d_in, const int* in_sizes, int n_in,
                              void* d_out, int out_size, void* d_ws, size_t ws_size,
                              hipStream_t stream) {
    const float* x        = (const float*)d_in[0];
    const float* q_down_w = (const float*)d_in[1];
    const float* q_down_b = (const float*)d_in[2];
    const float* q_norm_w = (const float*)d_in[3];
    const float* q_up_w   = (const float*)d_in[4];
    const float* q_up_b   = (const float*)d_in[5];
    const float* kv_down_w= (const float*)d_in[6];
    const float* kv_down_b= (const float*)d_in[7];
    const float* kv_norm_w= (const float*)d_in[8];
    const float* kv_up_w  = (const float*)d_in[9];
    const float* kv_up_b  = (const float*)d_in[10];
    const float* k_rope_w = (const float*)d_in[11];
    const float* k_rope_b = (const float*)d_in[12];
    const float* out_w    = (const float*)d_in[13];
    const float* out_b    = (const float*)d_in[14];

    char* ws = (char*)d_ws;
    u16* xbf    = (u16*)(ws + 0);          // 16.78 MB ; later reused as vT
    u16* wcat   = (u16*)(ws + 16777216);   // 10.49 MB (2560x2048 bf16)
    u16* quw    = (u16*)(ws + 27262976);   // 4.19 MB
    u16* kvuw   = (u16*)(ws + 31457280);   // 3.15 MB
    u16* outw   = (u16*)(ws + 34603008);   // 8.39 MB
    float* bcat = (float*)(ws + 42991616); // 10 KB (pad to 16 KB)
    float* dcat = (float*)(ws + 43008000); // 25.17 MB (4096x1536 f32); reused as attnbuf
    u16* cq     = (u16*)(ws + 68173824);   // 8.39 MB
    u16* ckv    = (u16*)(ws + 76562432);   // 4.19 MB
    u16* qbuf   = (u16*)(ws + 80756736);   // 16.78 MB
    u16* kvbuf  = (u16*)(ws + 97533952);   // 25.17 MB
    u16* krbuf  = (u16*)(ws + 122699776);  // 8.39 MB  (end 131,088,384)
    u16* vT     = (u16*)(ws + 0);          // alias xbf (dead after gemm_down)
    u16* attnbuf= (u16*)(ws + 43008000);   // alias dcat (dead after rmsnorms)

    cvt_all<<<20993, 256, 0, stream>>>(
        x, xbf,
        q_down_w,  wcat,
        kv_down_w, wcat + 1024 * 2048,
        k_rope_w,  wcat + 1536 * 2048,
        q_up_w,    quw,
        kv_up_w,   kvuw,
        out_w,     outw,
        q_down_b, kv_down_b, k_rope_b, bcat);

    // fused down projections: x @ [q_down|kv_down|k_rope]^T
    gemm_down<<<dim3(20, 32), 256, 0, stream>>>(xbf, wcat, bcat, dcat, krbuf);
    rmsnorm_bf16<1024><<<MROWS, 256, 0, stream>>>(dcat, 1536, q_norm_w, cq);
    rmsnorm_bf16<512><<<MROWS, 256, 0, stream>>>(dcat + 1024, 1536, kv_norm_w, ckv);
    // up projections; kv_up writes V directly transposed into vT (xbf dead)
    gemm_bt<u16><<<dim3(16, 32), 256, 0, stream>>>(cq, quw, q_up_b, qbuf, MROWS, 2048, 1024);
    gemm_kvup<<<dim3(24, 32), 256, 0, stream>>>(ckv, kvuw, kv_up_b, kvbuf, vT);
    // attention: 512 blocks x 512 threads, K-split, 64KB LDS
    mla_attn<<<dim3(32, 16), 512, 0, stream>>>(qbuf, kvbuf, krbuf, vT, attnbuf);
    // output projection
    gemm_bt<float><<<dim3(16, 32), 256, 0, stream>>>(attnbuf, outw, out_b, (float*)d_out, MROWS, 2048, 2048);
}